// Round 1
// baseline (474.998 us; speedup 1.0000x reference)
//
#include <hip/hip_runtime.h>
#include <math.h>

#define HDIM 128
#define S 16            // samples per workgroup
#define STR 132         // padded stride (floats) for per-sample 128-vectors
#define NT 256

// tanh(x) = 1 - 2/(exp(2x)+1): NaN-free for any x (x->+inf: 1-0; x->-inf: 1-2),
// abs err ~1e-7 (v_exp_f32 + v_rcp_f32), vs ocml's branchy ~20-op sequence.
__device__ __forceinline__ float tanh_fast(float x){
    const float e = __expf(2.0f * x);
    return 1.0f - 2.0f * __builtin_amdgcn_rcpf(e + 1.0f);
}

// Fused dynamics kernel, v2:
//  - c1 = W1*a0 GEMV eliminated via  sum_j u1_j c1_j == t . a0  (t = W1^T u1, already
//    needed for the gradient) -> stage B is 2 GEMVs, a0 never materialized.
//  - S=16, u1/g/hvv reductions in registers via __shfl / __shfl_xor butterflies:
//    LDS 61.4KB -> ~24KB (6 blocks/CU), barriers 6 -> 2, no atomics.
//  - 2 samples/thread in stages B/C to amortize W1 cache traffic.
__global__ __launch_bounds__(NT, 5)
void dyn_kernel(const float* __restrict__ X, const float* __restrict__ Km,
                const float* __restrict__ Dm, const float* __restrict__ W0,
                const float* __restrict__ b0, const float* __restrict__ W1,
                const float* __restrict__ b1, const float* __restrict__ W2,
                float* __restrict__ out)
{
    __shared__ float xt[S * 16];          // 1 KB
    __shared__ float W0s[HDIM * 8];       // 4 KB
    __shared__ float b0s[HDIM], b1s[HDIM], W2s[HDIM];   // 1.5 KB
    __shared__ float Ks[64], Ds[64];      // 0.5 KB
    __shared__ float h0s[S * STR];        // 8.25 KB
    __shared__ float dh0s[S * STR];       // 8.25 KB   -> total ~23.5 KB

    const int tid = threadIdx.x;
    const long base = (long)blockIdx.x * S;   // first sample of this workgroup

    // ---------------- load weights + X tile ----------------
    if (tid < 64) ((float4*)xt)[tid] = ((const float4*)(X + base * 16))[tid];
    ((float4*)W0s)[tid] = ((const float4*)W0)[tid];            // 256 float4
    if (tid < 32)        ((float4*)b0s)[tid]       = ((const float4*)b0)[tid];
    else if (tid < 64)   ((float4*)b1s)[tid - 32]  = ((const float4*)b1)[tid - 32];
    else if (tid < 96)   ((float4*)W2s)[tid - 64]  = ((const float4*)W2)[tid - 64];
    else if (tid < 112)  ((float4*)Ks)[tid - 96]   = ((const float4*)Km)[tid - 96];
    else if (tid < 128)  ((float4*)Ds)[tid - 112]  = ((const float4*)Dm)[tid - 112];
    __syncthreads();

    // ---------------- stage A: h0 = tanh(W0 x + b0), dh0 = e0 * (W0 v) ----------------
    {
        const int s = tid >> 4;        // 0..15 sample
        const int p = tid & 15;        // 0..15 -> hidden units 8p..8p+7
        float xr[16];
        #pragma unroll
        for (int q = 0; q < 4; ++q) ((float4*)xr)[q] = ((const float4*)&xt[s * 16])[q];
        float h0r[8], d0r[8];
        #pragma unroll
        for (int i = 0; i < 8; ++i) {
            const int k = p * 8 + i;
            const float4 wa = ((const float4*)&W0s[k * 8])[0];
            const float4 wb = ((const float4*)&W0s[k * 8])[1];
            float z = b0s[k];
            z = fmaf(wa.x, xr[0], z); z = fmaf(wa.y, xr[1], z);
            z = fmaf(wa.z, xr[2], z); z = fmaf(wa.w, xr[3], z);
            z = fmaf(wb.x, xr[4], z); z = fmaf(wb.y, xr[5], z);
            z = fmaf(wb.z, xr[6], z); z = fmaf(wb.w, xr[7], z);
            float dz = wa.x * xr[8];
            dz = fmaf(wa.y, xr[9],  dz); dz = fmaf(wa.z, xr[10], dz); dz = fmaf(wa.w, xr[11], dz);
            dz = fmaf(wb.x, xr[12], dz); dz = fmaf(wb.y, xr[13], dz);
            dz = fmaf(wb.z, xr[14], dz); dz = fmaf(wb.w, xr[15], dz);
            const float h = tanh_fast(z);
            const float e = fmaf(-h, h, 1.0f);
            h0r[i] = h; d0r[i] = e * dz;
        }
        float4* hp = (float4*)&h0s[s * STR + p * 8];
        hp[0] = make_float4(h0r[0], h0r[1], h0r[2], h0r[3]);
        hp[1] = make_float4(h0r[4], h0r[5], h0r[6], h0r[7]);
        float4* dp = (float4*)&dh0s[s * STR + p * 8];
        dp[0] = make_float4(d0r[0], d0r[1], d0r[2], d0r[3]);
        dp[1] = make_float4(d0r[4], d0r[5], d0r[6], d0r[7]);
    }
    __syncthreads();

    // thread decomposition for stages B and C (identical lane->sample map; no barrier needed)
    const int jg  = tid & 31;          // 32 groups x 4 outputs
    const int sgp = tid >> 5;          // 8 groups x 2 samples
    const int s0 = sgp * 2, s1 = s0 + 1;
    const int jbase = jg * 4;
    const int lanehi = tid & 32;       // hi half-wave flag (== lane & 32)

    // ---------------- stage B: z1 = W1 h0 + b1 ; dz1 = W1 dh0 ----------------
    float az0[4] = {0,0,0,0}, az1[4] = {0,0,0,0};
    float ad0[4] = {0,0,0,0}, ad1[4] = {0,0,0,0};
    {
        const float4* h0p0 = (const float4*)&h0s[s0 * STR];
        const float4* h0p1 = (const float4*)&h0s[s1 * STR];
        const float4* d0p0 = (const float4*)&dh0s[s0 * STR];
        const float4* d0p1 = (const float4*)&dh0s[s1 * STR];
        const float4* wr0 = (const float4*)&W1[(jbase + 0) * HDIM];
        const float4* wr1 = (const float4*)&W1[(jbase + 1) * HDIM];
        const float4* wr2 = (const float4*)&W1[(jbase + 2) * HDIM];
        const float4* wr3 = (const float4*)&W1[(jbase + 3) * HDIM];
        for (int kb = 0; kb < 32; ++kb) {
            const float4 ha = h0p0[kb], hb = h0p1[kb];
            const float4 da = d0p0[kb], db = d0p1[kb];
            const float4 w0v = wr0[kb], w1v = wr1[kb], w2v = wr2[kb], w3v = wr3[kb];
            #pragma unroll
            for (int jj = 0; jj < 4; ++jj) {
                const float4 w = (jj == 0) ? w0v : (jj == 1) ? w1v : (jj == 2) ? w2v : w3v;
                az0[jj] = fmaf(w.x, ha.x, az0[jj]); az0[jj] = fmaf(w.y, ha.y, az0[jj]);
                az0[jj] = fmaf(w.z, ha.z, az0[jj]); az0[jj] = fmaf(w.w, ha.w, az0[jj]);
                az1[jj] = fmaf(w.x, hb.x, az1[jj]); az1[jj] = fmaf(w.y, hb.y, az1[jj]);
                az1[jj] = fmaf(w.z, hb.z, az1[jj]); az1[jj] = fmaf(w.w, hb.w, az1[jj]);
                ad0[jj] = fmaf(w.x, da.x, ad0[jj]); ad0[jj] = fmaf(w.y, da.y, ad0[jj]);
                ad0[jj] = fmaf(w.z, da.z, ad0[jj]); ad0[jj] = fmaf(w.w, da.w, ad0[jj]);
                ad1[jj] = fmaf(w.x, db.x, ad1[jj]); ad1[jj] = fmaf(w.y, db.y, ad1[jj]);
                ad1[jj] = fmaf(w.z, db.z, ad1[jj]); ad1[jj] = fmaf(w.w, db.w, ad1[jj]);
            }
        }
    }

    // stage B epilogue: u1 = w2*e1 (registers), hvv part2 = -2 sum w2 h1 e1 dz1^2
    float u1r0[4], u1r1[4];
    float hv0 = 0.f, hv1 = 0.f;
    #pragma unroll
    for (int jj = 0; jj < 4; ++jj) {
        const int j = jbase + jj;
        const float bb = b1s[j], w2 = W2s[j];
        const float h1a = tanh_fast(az0[jj] + bb);
        const float e1a = fmaf(-h1a, h1a, 1.f);
        u1r0[jj] = w2 * e1a;
        hv0 = fmaf(-2.f * w2 * h1a * e1a, ad0[jj] * ad0[jj], hv0);
        const float h1b = tanh_fast(az1[jj] + bb);
        const float e1b = fmaf(-h1b, h1b, 1.f);
        u1r1[jj] = w2 * e1b;
        hv1 = fmaf(-2.f * w2 * h1b * e1b, ad1[jj] * ad1[jj], hv1);
    }
    // no __syncthreads: stage C reads h0s/dh0s (unmodified) and u1 via intra-wave shfl

    // ---------------- stage C: t = W1^T u1 via shfl; u0; g partials; hvv part1 = t.a0 ----------------
    const int ibase = jg * 4;          // this thread owns hidden rows ibase..ibase+3
    float t0[4] = {0,0,0,0}, t1[4] = {0,0,0,0};
    {
        const float4* wcol = (const float4*)(W1 + ibase);   // wcol[j*32] = W1[j][ibase..+3]
        for (int jb = 0; jb < 32; ++jb) {
            const int src = jb + lanehi;                    // lane holding u1[j] for my samples
            #pragma unroll
            for (int q = 0; q < 4; ++q) {
                const float ua = __shfl(u1r0[q], src);
                const float ub = __shfl(u1r1[q], src);
                const float4 wv = wcol[(jb * 4 + q) * 32];
                t0[0] = fmaf(ua, wv.x, t0[0]); t0[1] = fmaf(ua, wv.y, t0[1]);
                t0[2] = fmaf(ua, wv.z, t0[2]); t0[3] = fmaf(ua, wv.w, t0[3]);
                t1[0] = fmaf(ub, wv.x, t1[0]); t1[1] = fmaf(ub, wv.y, t1[1]);
                t1[2] = fmaf(ub, wv.z, t1[2]); t1[3] = fmaf(ub, wv.w, t1[3]);
            }
        }
    }

    float gp0[8] = {0,0,0,0,0,0,0,0}, gp1[8] = {0,0,0,0,0,0,0,0};
    {
        float h0av[4], h0bv[4], d0av[4], d0bv[4];
        {
            const float4 a = *(const float4*)&h0s[s0 * STR + ibase];
            h0av[0] = a.x; h0av[1] = a.y; h0av[2] = a.z; h0av[3] = a.w;
            const float4 b = *(const float4*)&h0s[s1 * STR + ibase];
            h0bv[0] = b.x; h0bv[1] = b.y; h0bv[2] = b.z; h0bv[3] = b.w;
            const float4 c = *(const float4*)&dh0s[s0 * STR + ibase];
            d0av[0] = c.x; d0av[1] = c.y; d0av[2] = c.z; d0av[3] = c.w;
            const float4 d = *(const float4*)&dh0s[s1 * STR + ibase];
            d0bv[0] = d.x; d0bv[1] = d.y; d0bv[2] = d.z; d0bv[3] = d.w;
        }
        #pragma unroll
        for (int ii = 0; ii < 4; ++ii) {
            const int i = ibase + ii;
            const float ha = h0av[ii], hb = h0bv[ii];
            const float da_ = d0av[ii], db_ = d0bv[ii];
            const float ea = fmaf(-ha, ha, 1.f), eb = fmaf(-hb, hb, 1.f);
            const float u0a = ea * t0[ii], u0b = eb * t1[ii];
            // a0_i = -2 h0 e0 dz0^2 = -2 h0 dh0^2 / e0 ; hvv part1 += t_i a0_i
            hv0 = fmaf(-2.f * ha * da_ * da_ * t0[ii],
                       __builtin_amdgcn_rcpf(fmaxf(ea, 1e-20f)), hv0);
            hv1 = fmaf(-2.f * hb * db_ * db_ * t1[ii],
                       __builtin_amdgcn_rcpf(fmaxf(eb, 1e-20f)), hv1);
            const float4 wa = ((const float4*)&W0s[i * 8])[0];
            const float4 wb = ((const float4*)&W0s[i * 8])[1];
            gp0[0] = fmaf(wa.x, u0a, gp0[0]); gp0[1] = fmaf(wa.y, u0a, gp0[1]);
            gp0[2] = fmaf(wa.z, u0a, gp0[2]); gp0[3] = fmaf(wa.w, u0a, gp0[3]);
            gp0[4] = fmaf(wb.x, u0a, gp0[4]); gp0[5] = fmaf(wb.y, u0a, gp0[5]);
            gp0[6] = fmaf(wb.z, u0a, gp0[6]); gp0[7] = fmaf(wb.w, u0a, gp0[7]);
            gp1[0] = fmaf(wa.x, u0b, gp1[0]); gp1[1] = fmaf(wa.y, u0b, gp1[1]);
            gp1[2] = fmaf(wa.z, u0b, gp1[2]); gp1[3] = fmaf(wa.w, u0b, gp1[3]);
            gp1[4] = fmaf(wb.x, u0b, gp1[4]); gp1[5] = fmaf(wb.y, u0b, gp1[5]);
            gp1[6] = fmaf(wb.z, u0b, gp1[6]); gp1[7] = fmaf(wb.w, u0b, gp1[7]);
        }
    }

    // ---------------- butterfly reduce g (2x8) and hvv (2) over the 32-lane half ----------------
    #pragma unroll
    for (int m = 1; m <= 16; m <<= 1) {
        #pragma unroll
        for (int d = 0; d < 8; ++d) {
            gp0[d] += __shfl_xor(gp0[d], m);
            gp1[d] += __shfl_xor(gp1[d], m);
        }
        hv0 += __shfl_xor(hv0, m);
        hv1 += __shfl_xor(hv1, m);
    }

    // ---------------- force, alpha, output ----------------
    float f0[8], f1[8];
    {
        float xr0[16], xr1[16];
        #pragma unroll
        for (int q = 0; q < 4; ++q) {
            ((float4*)xr0)[q] = ((const float4*)&xt[s0 * 16])[q];
            ((float4*)xr1)[q] = ((const float4*)&xt[s1 * 16])[q];
        }
        #pragma unroll
        for (int d = 0; d < 8; ++d) {
            const float4 ka = ((const float4*)&Ks[d * 8])[0];
            const float4 kb = ((const float4*)&Ks[d * 8])[1];
            const float4 ea = ((const float4*)&Ds[d * 8])[0];
            const float4 eb = ((const float4*)&Ds[d * 8])[1];
            float fa = ka.x * xr0[0];
            fa = fmaf(ka.y, xr0[1], fa); fa = fmaf(ka.z, xr0[2], fa); fa = fmaf(ka.w, xr0[3], fa);
            fa = fmaf(kb.x, xr0[4], fa); fa = fmaf(kb.y, xr0[5], fa);
            fa = fmaf(kb.z, xr0[6], fa); fa = fmaf(kb.w, xr0[7], fa);
            fa = fmaf(ea.x, xr0[8],  fa); fa = fmaf(ea.y, xr0[9],  fa);
            fa = fmaf(ea.z, xr0[10], fa); fa = fmaf(ea.w, xr0[11], fa);
            fa = fmaf(eb.x, xr0[12], fa); fa = fmaf(eb.y, xr0[13], fa);
            fa = fmaf(eb.z, xr0[14], fa); fa = fmaf(eb.w, xr0[15], fa);
            f0[d] = -fa;
            float fb = ka.x * xr1[0];
            fb = fmaf(ka.y, xr1[1], fb); fb = fmaf(ka.z, xr1[2], fb); fb = fmaf(ka.w, xr1[3], fb);
            fb = fmaf(kb.x, xr1[4], fb); fb = fmaf(kb.y, xr1[5], fb);
            fb = fmaf(kb.z, xr1[6], fb); fb = fmaf(kb.w, xr1[7], fb);
            fb = fmaf(ea.x, xr1[8],  fb); fb = fmaf(ea.y, xr1[9],  fb);
            fb = fmaf(ea.z, xr1[10], fb); fb = fmaf(ea.w, xr1[11], fb);
            fb = fmaf(eb.x, xr1[12], fb); fb = fmaf(eb.y, xr1[13], fb);
            fb = fmaf(eb.z, xr1[14], fb); fb = fmaf(eb.w, xr1[15], fb);
            f1[d] = -fb;
        }
    }

    float gf0 = 0.f, gg0 = 0.f, gf1 = 0.f, gg1 = 0.f;
    #pragma unroll
    for (int d = 0; d < 8; ++d) {
        gf0 = fmaf(gp0[d], f0[d], gf0); gg0 = fmaf(gp0[d], gp0[d], gg0);
        gf1 = fmaf(gp1[d], f1[d], gf1); gg1 = fmaf(gp1[d], gp1[d], gg1);
    }
    const float al0 = (gf0 + hv0) / (1.f + gg0);
    const float al1 = (gf1 + hv1) / (1.f + gg1);

    float o0 = 0.f, o1 = 0.f;
    #pragma unroll
    for (int d = 0; d < 8; ++d) {
        if (jg == d) {                 // compile-time index into reg arrays (no scratch)
            o0 = fmaf(-gp0[d], al0, f0[d]);
            o1 = fmaf(-gp1[d], al1, f1[d]);
        }
    }
    if (jg < 8) {
        out[(base + s0) * 8 + jg] = o0;
        out[(base + s1) * 8 + jg] = o1;
    }
}

extern "C" void kernel_launch(void* const* d_in, const int* in_sizes, int n_in,
                              void* d_out, int out_size, void* d_ws, size_t ws_size,
                              hipStream_t stream) {
    const float* X  = (const float*)d_in[0];
    const float* Km = (const float*)d_in[1];
    const float* Dm = (const float*)d_in[2];
    const float* W0 = (const float*)d_in[3];
    const float* b0 = (const float*)d_in[4];
    const float* W1 = (const float*)d_in[5];
    const float* b1 = (const float*)d_in[6];
    const float* W2 = (const float*)d_in[7];
    // d_in[8] = b2 (unused: cancels in grad/hessian/force)
    float* out = (float*)d_out;

    const int BATCH = in_sizes[0] / 16;        // 65536
    const int nblocks = BATCH / S;             // 4096
    dyn_kernel<<<nblocks, NT, 0, stream>>>(X, Km, Dm, W0, b0, W1, b1, W2, out);
}

// Round 2
// 358.530 us; speedup vs baseline: 1.3248x; 1.3248x over previous
//
#include <hip/hip_runtime.h>
#include <math.h>

#define HDIM 128
#define S 16            // samples per workgroup
#define STR 132         // padded stride (floats) for per-sample 128-vectors
#define NT 256

// tanh(x) = 1 - 2/(exp(2x)+1): NaN-free for any x (x->+inf: 1-0; x->-inf: 1-2),
// abs err ~1e-7 (v_exp_f32 + v_rcp_f32), vs ocml's branchy ~20-op sequence.
__device__ __forceinline__ float tanh_fast(float x){
    const float e = __expf(2.0f * x);
    return 1.0f - 2.0f * __builtin_amdgcn_rcpf(e + 1.0f);
}

// v3: v2 algorithm (c1-GEMV eliminated, register reductions, 2 barriers) with the
// register budget fixed:
//  - __launch_bounds__(NT,4): VGPR cap 128 (v2's (NT,5) quantized the cap to ~64 ->
//    48 VGPRs + ~270 MB/dispatch scratch spill traffic = the whole regression).
//  - Tail rewritten register-light: per-lane force row d=jg&7, folding butterfly for g
//    (no f[8]/xr[16] arrays live at peak).
__global__ __launch_bounds__(NT, 4)
void dyn_kernel(const float* __restrict__ X, const float* __restrict__ Km,
                const float* __restrict__ Dm, const float* __restrict__ W0,
                const float* __restrict__ b0, const float* __restrict__ W1,
                const float* __restrict__ b1, const float* __restrict__ W2,
                float* __restrict__ out)
{
    __shared__ float xt[S * 16];          // 1 KB
    __shared__ float W0s[HDIM * 8];       // 4 KB
    __shared__ float b0s[HDIM], b1s[HDIM], W2s[HDIM];   // 1.5 KB
    __shared__ float Ks[64], Ds[64];      // 0.5 KB
    __shared__ float h0s[S * STR];        // 8.25 KB
    __shared__ float dh0s[S * STR];       // 8.25 KB   -> total ~23.9 KB (6 blocks/CU)

    const int tid = threadIdx.x;
    const long base = (long)blockIdx.x * S;

    // ---------------- load weights + X tile ----------------
    if (tid < 64) ((float4*)xt)[tid] = ((const float4*)(X + base * 16))[tid];
    ((float4*)W0s)[tid] = ((const float4*)W0)[tid];            // 256 float4
    if (tid < 32)        ((float4*)b0s)[tid]       = ((const float4*)b0)[tid];
    else if (tid < 64)   ((float4*)b1s)[tid - 32]  = ((const float4*)b1)[tid - 32];
    else if (tid < 96)   ((float4*)W2s)[tid - 64]  = ((const float4*)W2)[tid - 64];
    else if (tid < 112)  ((float4*)Ks)[tid - 96]   = ((const float4*)Km)[tid - 96];
    else if (tid < 128)  ((float4*)Ds)[tid - 112]  = ((const float4*)Dm)[tid - 112];
    __syncthreads();

    // ---------------- stage A: h0 = tanh(W0 x + b0), dh0 = e0 * (W0 v) ----------------
    {
        const int s = tid >> 4;        // 0..15 sample
        const int p = tid & 15;        // hidden units 8p..8p+7
        float xr[16];
        #pragma unroll
        for (int q = 0; q < 4; ++q) ((float4*)xr)[q] = ((const float4*)&xt[s * 16])[q];
        float h0r[8], d0r[8];
        #pragma unroll
        for (int i = 0; i < 8; ++i) {
            const int k = p * 8 + i;
            const float4 wa = ((const float4*)&W0s[k * 8])[0];
            const float4 wb = ((const float4*)&W0s[k * 8])[1];
            float z = b0s[k];
            z = fmaf(wa.x, xr[0], z); z = fmaf(wa.y, xr[1], z);
            z = fmaf(wa.z, xr[2], z); z = fmaf(wa.w, xr[3], z);
            z = fmaf(wb.x, xr[4], z); z = fmaf(wb.y, xr[5], z);
            z = fmaf(wb.z, xr[6], z); z = fmaf(wb.w, xr[7], z);
            float dz = wa.x * xr[8];
            dz = fmaf(wa.y, xr[9],  dz); dz = fmaf(wa.z, xr[10], dz); dz = fmaf(wa.w, xr[11], dz);
            dz = fmaf(wb.x, xr[12], dz); dz = fmaf(wb.y, xr[13], dz);
            dz = fmaf(wb.z, xr[14], dz); dz = fmaf(wb.w, xr[15], dz);
            const float h = tanh_fast(z);
            const float e = fmaf(-h, h, 1.0f);
            h0r[i] = h; d0r[i] = e * dz;
        }
        float4* hp = (float4*)&h0s[s * STR + p * 8];
        hp[0] = make_float4(h0r[0], h0r[1], h0r[2], h0r[3]);
        hp[1] = make_float4(h0r[4], h0r[5], h0r[6], h0r[7]);
        float4* dp = (float4*)&dh0s[s * STR + p * 8];
        dp[0] = make_float4(d0r[0], d0r[1], d0r[2], d0r[3]);
        dp[1] = make_float4(d0r[4], d0r[5], d0r[6], d0r[7]);
    }
    __syncthreads();

    // thread decomposition for stages B and C (identical lane->sample map; no barrier needed)
    const int jg  = tid & 31;          // 32 groups x 4 outputs / rows
    const int sgp = tid >> 5;          // 8 groups x 2 samples
    const int s0 = sgp * 2, s1 = s0 + 1;
    const int jbase = jg * 4;
    const int lanehi = tid & 32;       // hi half-wave flag

    // ---------------- stage B: z1 = W1 h0 + b1 ; dz1 = W1 dh0 ----------------
    float az0[4] = {0,0,0,0}, az1[4] = {0,0,0,0};
    float ad0[4] = {0,0,0,0}, ad1[4] = {0,0,0,0};
    {
        const float4* h0p0 = (const float4*)&h0s[s0 * STR];
        const float4* h0p1 = (const float4*)&h0s[s1 * STR];
        const float4* d0p0 = (const float4*)&dh0s[s0 * STR];
        const float4* d0p1 = (const float4*)&dh0s[s1 * STR];
        const float4* wr0 = (const float4*)&W1[(jbase + 0) * HDIM];
        const float4* wr1 = (const float4*)&W1[(jbase + 1) * HDIM];
        const float4* wr2 = (const float4*)&W1[(jbase + 2) * HDIM];
        const float4* wr3 = (const float4*)&W1[(jbase + 3) * HDIM];
        for (int kb = 0; kb < 32; ++kb) {
            const float4 ha = h0p0[kb], hb = h0p1[kb];
            const float4 da = d0p0[kb], db = d0p1[kb];
            const float4 w0v = wr0[kb], w1v = wr1[kb], w2v = wr2[kb], w3v = wr3[kb];
            #pragma unroll
            for (int jj = 0; jj < 4; ++jj) {
                const float4 w = (jj == 0) ? w0v : (jj == 1) ? w1v : (jj == 2) ? w2v : w3v;
                az0[jj] = fmaf(w.x, ha.x, az0[jj]); az0[jj] = fmaf(w.y, ha.y, az0[jj]);
                az0[jj] = fmaf(w.z, ha.z, az0[jj]); az0[jj] = fmaf(w.w, ha.w, az0[jj]);
                az1[jj] = fmaf(w.x, hb.x, az1[jj]); az1[jj] = fmaf(w.y, hb.y, az1[jj]);
                az1[jj] = fmaf(w.z, hb.z, az1[jj]); az1[jj] = fmaf(w.w, hb.w, az1[jj]);
                ad0[jj] = fmaf(w.x, da.x, ad0[jj]); ad0[jj] = fmaf(w.y, da.y, ad0[jj]);
                ad0[jj] = fmaf(w.z, da.z, ad0[jj]); ad0[jj] = fmaf(w.w, da.w, ad0[jj]);
                ad1[jj] = fmaf(w.x, db.x, ad1[jj]); ad1[jj] = fmaf(w.y, db.y, ad1[jj]);
                ad1[jj] = fmaf(w.z, db.z, ad1[jj]); ad1[jj] = fmaf(w.w, db.w, ad1[jj]);
            }
        }
    }

    // stage B epilogue: u1 = w2*e1 (registers), hvv part2 = -2 sum w2 h1 e1 dz1^2
    float u1r0[4], u1r1[4];
    float hv0 = 0.f, hv1 = 0.f;
    #pragma unroll
    for (int jj = 0; jj < 4; ++jj) {
        const int j = jbase + jj;
        const float bb = b1s[j], w2 = W2s[j];
        const float h1a = tanh_fast(az0[jj] + bb);
        const float e1a = fmaf(-h1a, h1a, 1.f);
        u1r0[jj] = w2 * e1a;
        hv0 = fmaf(-2.f * w2 * h1a * e1a, ad0[jj] * ad0[jj], hv0);
        const float h1b = tanh_fast(az1[jj] + bb);
        const float e1b = fmaf(-h1b, h1b, 1.f);
        u1r1[jj] = w2 * e1b;
        hv1 = fmaf(-2.f * w2 * h1b * e1b, ad1[jj] * ad1[jj], hv1);
    }
    // no __syncthreads: stage C reads h0s/dh0s (unmodified) and u1 via intra-wave shfl

    // ---------------- stage C: t = W1^T u1 via shfl; u0; g partials; hvv part1 = t.a0 ----------------
    const int ibase = jg * 4;          // this thread owns hidden rows ibase..ibase+3
    float t0[4] = {0,0,0,0}, t1[4] = {0,0,0,0};
    {
        const float4* wcol = (const float4*)(W1 + ibase);   // wcol[j*32] = W1[j][ibase..+3]
        for (int jb = 0; jb < 32; ++jb) {
            const int src = jb + lanehi;                    // lane holding u1[j] for my samples
            #pragma unroll
            for (int q = 0; q < 4; ++q) {
                const float ua = __shfl(u1r0[q], src);
                const float ub = __shfl(u1r1[q], src);
                const float4 wv = wcol[(jb * 4 + q) * 32];
                t0[0] = fmaf(ua, wv.x, t0[0]); t0[1] = fmaf(ua, wv.y, t0[1]);
                t0[2] = fmaf(ua, wv.z, t0[2]); t0[3] = fmaf(ua, wv.w, t0[3]);
                t1[0] = fmaf(ub, wv.x, t1[0]); t1[1] = fmaf(ub, wv.y, t1[1]);
                t1[2] = fmaf(ub, wv.z, t1[2]); t1[3] = fmaf(ub, wv.w, t1[3]);
            }
        }
    }

    float gp0[8] = {0,0,0,0,0,0,0,0}, gp1[8] = {0,0,0,0,0,0,0,0};
    {
        #pragma unroll
        for (int ii = 0; ii < 4; ++ii) {
            const int i = ibase + ii;
            const float ha = h0s[s0 * STR + i];
            const float hb = h0s[s1 * STR + i];
            const float da_ = dh0s[s0 * STR + i];
            const float db_ = dh0s[s1 * STR + i];
            const float ea = fmaf(-ha, ha, 1.f), eb = fmaf(-hb, hb, 1.f);
            const float u0a = ea * t0[ii], u0b = eb * t1[ii];
            // a0_i = -2 h0 e0 dz0^2 = -2 h0 dh0^2 / e0 ; hvv part1 += t_i a0_i
            hv0 = fmaf(-2.f * ha * da_ * da_ * t0[ii],
                       __builtin_amdgcn_rcpf(fmaxf(ea, 1e-20f)), hv0);
            hv1 = fmaf(-2.f * hb * db_ * db_ * t1[ii],
                       __builtin_amdgcn_rcpf(fmaxf(eb, 1e-20f)), hv1);
            const float4 wa = ((const float4*)&W0s[i * 8])[0];
            const float4 wb = ((const float4*)&W0s[i * 8])[1];
            gp0[0] = fmaf(wa.x, u0a, gp0[0]); gp0[1] = fmaf(wa.y, u0a, gp0[1]);
            gp0[2] = fmaf(wa.z, u0a, gp0[2]); gp0[3] = fmaf(wa.w, u0a, gp0[3]);
            gp0[4] = fmaf(wb.x, u0a, gp0[4]); gp0[5] = fmaf(wb.y, u0a, gp0[5]);
            gp0[6] = fmaf(wb.z, u0a, gp0[6]); gp0[7] = fmaf(wb.w, u0a, gp0[7]);
            gp1[0] = fmaf(wa.x, u0b, gp1[0]); gp1[1] = fmaf(wa.y, u0b, gp1[1]);
            gp1[2] = fmaf(wa.z, u0b, gp1[2]); gp1[3] = fmaf(wa.w, u0b, gp1[3]);
            gp1[4] = fmaf(wb.x, u0b, gp1[4]); gp1[5] = fmaf(wb.y, u0b, gp1[5]);
            gp1[6] = fmaf(wb.z, u0b, gp1[6]); gp1[7] = fmaf(wb.w, u0b, gp1[7]);
        }
    }

    // ---------------- reductions (register-light) ----------------
    // hvv: full 32-lane butterfly
    #pragma unroll
    for (int m = 1; m <= 16; m <<= 1) {
        hv0 += __shfl_xor(hv0, m);
        hv1 += __shfl_xor(hv1, m);
    }
    // g: masks 8,16 full (now value depends only on jg&7), then fold 4/2/1 so that
    // lane jg ends holding the TOTAL g[jg&7]. No 8-wide array survives.
    #pragma unroll
    for (int m = 8; m <= 16; m <<= 1) {
        #pragma unroll
        for (int d = 0; d < 8; ++d) {
            gp0[d] += __shfl_xor(gp0[d], m);
            gp1[d] += __shfl_xor(gp1[d], m);
        }
    }
    float b0r[4], b1r[4];
    {
        const int hi4 = jg & 4;
        #pragma unroll
        for (int d = 0; d < 4; ++d) {
            const float lo0 = gp0[d]     + __shfl_xor(gp0[d], 4);
            const float hi0 = gp0[d + 4] + __shfl_xor(gp0[d + 4], 4);
            b0r[d] = hi4 ? hi0 : lo0;
            const float lo1 = gp1[d]     + __shfl_xor(gp1[d], 4);
            const float hi1 = gp1[d + 4] + __shfl_xor(gp1[d + 4], 4);
            b1r[d] = hi4 ? hi1 : lo1;
        }
    }
    float c0r[2], c1r[2];
    {
        const int hi2 = jg & 2;
        #pragma unroll
        for (int d = 0; d < 2; ++d) {
            const float lo0 = b0r[d]     + __shfl_xor(b0r[d], 2);
            const float hi0 = b0r[d + 2] + __shfl_xor(b0r[d + 2], 2);
            c0r[d] = hi2 ? hi0 : lo0;
            const float lo1 = b1r[d]     + __shfl_xor(b1r[d], 2);
            const float hi1 = b1r[d + 2] + __shfl_xor(b1r[d + 2], 2);
            c1r[d] = hi2 ? hi1 : lo1;
        }
    }
    float gv0, gv1;
    {
        const int hi1m = jg & 1;
        const float lo0 = c0r[0] + __shfl_xor(c0r[0], 1);
        const float hi0 = c0r[1] + __shfl_xor(c0r[1], 1);
        gv0 = hi1m ? hi0 : lo0;        // = total g[jg&7], sample s0
        const float lo1 = c1r[0] + __shfl_xor(c1r[0], 1);
        const float hi1 = c1r[1] + __shfl_xor(c1r[1], 1);
        gv1 = hi1m ? hi1 : lo1;        // sample s1
    }

    // ---------------- force (per-lane row d = jg&7), alpha, output ----------------
    const int dd = jg & 7;
    float fd0, fd1;
    {
        const float* xv0 = &xt[s0 * 16];
        const float* xv1 = &xt[s1 * 16];
        const float* Kr = &Ks[dd * 8];
        const float* Dr = &Ds[dd * 8];
        float a = 0.f, b = 0.f;
        #pragma unroll
        for (int k = 0; k < 8; ++k) {
            a = fmaf(Kr[k], xv0[k], a); a = fmaf(Dr[k], xv0[8 + k], a);
            b = fmaf(Kr[k], xv1[k], b); b = fmaf(Dr[k], xv1[8 + k], b);
        }
        fd0 = -a; fd1 = -b;
    }

    // gf = sum_d g[d] f[d], gg = |g|^2 over each 8-lane group (all groups identical)
    float p0 = gv0 * fd0, q0 = gv0 * gv0;
    float p1 = gv1 * fd1, q1 = gv1 * gv1;
    #pragma unroll
    for (int m = 1; m <= 4; m <<= 1) {
        p0 += __shfl_xor(p0, m); q0 += __shfl_xor(q0, m);
        p1 += __shfl_xor(p1, m); q1 += __shfl_xor(q1, m);
    }
    const float al0 = (p0 + hv0) * __builtin_amdgcn_rcpf(1.f + q0);
    const float al1 = (p1 + hv1) * __builtin_amdgcn_rcpf(1.f + q1);

    if (jg < 16) {                      // lanes 0-7: sample s0; lanes 8-15: sample s1
        const long sm = base + s0 + (jg >> 3);
        const float val = (jg < 8) ? fmaf(-gv0, al0, fd0) : fmaf(-gv1, al1, fd1);
        out[sm * 8 + dd] = val;
    }
}

extern "C" void kernel_launch(void* const* d_in, const int* in_sizes, int n_in,
                              void* d_out, int out_size, void* d_ws, size_t ws_size,
                              hipStream_t stream) {
    const float* X  = (const float*)d_in[0];
    const float* Km = (const float*)d_in[1];
    const float* Dm = (const float*)d_in[2];
    const float* W0 = (const float*)d_in[3];
    const float* b0 = (const float*)d_in[4];
    const float* W1 = (const float*)d_in[5];
    const float* b1 = (const float*)d_in[6];
    const float* W2 = (const float*)d_in[7];
    // d_in[8] = b2 (unused: cancels in grad/hessian/force)
    float* out = (float*)d_out;

    const int BATCH = in_sizes[0] / 16;        // 65536
    const int nblocks = BATCH / S;             // 4096
    dyn_kernel<<<nblocks, NT, 0, stream>>>(X, Km, Dm, W0, b0, W1, b1, W2, out);
}

// Round 3
// 228.683 us; speedup vs baseline: 2.0771x; 1.5678x over previous
//
#include <hip/hip_runtime.h>
#include <math.h>

#define HDIM 128
#define S 16            // samples per workgroup
#define NT 256

// tanh(x) = 1 - 2/(exp(2x)+1): NaN-free for any x, abs err ~1e-7.
__device__ __forceinline__ float tanh_fast(float x){
    const float e = __expf(2.0f * x);
    return 1.0f - 2.0f * __builtin_amdgcn_rcpf(e + 1.0f);
}

__device__ __forceinline__ void fma4(float4& a, const float4 w, const float s){
    a.x = fmaf(w.x, s, a.x); a.y = fmaf(w.y, s, a.y);
    a.z = fmaf(w.z, s, a.z); a.w = fmaf(w.w, s, a.w);
}

// Prep: WT[k][j] = W1[j][k]  (64 blocks x 256 threads, one element each).
__global__ void transpose128(const float* __restrict__ W1, float* __restrict__ WT){
    const int idx = blockIdx.x * 256 + threadIdx.x;   // coalesced read
    WT[(idx & 127) * HDIM + (idx >> 7)] = W1[idx];
}

// v4: kill the two serialized pipes found in v3's counters.
//  - Stage B reads WT (pre-transposed W1) coalesced: 8 line-touches/wave-load vs 32
//    for the old 2KB-strided row reads (~109us of TA serialization removed).
//  - u1 exchange via LDS broadcast (aliasing dead dh0s) instead of 256 ds_bpermute/thread.
//  - Stage A stores a0 = -2*h0*e0*dz0^2 directly -> hvv part1 = t.a0 (no rcp hack).
//  - All per-sample dataflow is intra-half-wave + in-order DS pipe -> ONE barrier total.
//  - W0/b0 from global (L1-hot 4KB); LDS 26.5KB -> up to 6 blocks/CU.
template<bool USE_WT>
__global__ __launch_bounds__(NT, 4)
void dyn_kernel(const float* __restrict__ X, const float* __restrict__ Km,
                const float* __restrict__ Dm, const float* __restrict__ W0,
                const float* __restrict__ b0, const float* __restrict__ W1,
                const float* __restrict__ WT, const float* __restrict__ b1,
                const float* __restrict__ W2, float* __restrict__ out)
{
    __shared__ float xt[S * 16];            // 1 KB
    __shared__ float b1s[HDIM], W2s[HDIM];  // 1 KB
    __shared__ float Ks[64], Ds[64];        // 0.5 KB
    __shared__ float h0s[S * HDIM];         // 8 KB
    __shared__ float dh0s[S * HDIM];        // 8 KB (aliased as u1s after stage B)
    __shared__ float a0s[S * HDIM];         // 8 KB

    const int tid = threadIdx.x;
    const long base = (long)blockIdx.x * S;

    // ---------------- load X tile + small weights (ONLY barrier in the kernel) ----
    if (tid < 64) ((float4*)xt)[tid] = ((const float4*)(X + base * 16))[tid];
    if (tid < 32)       ((float4*)b1s)[tid]      = ((const float4*)b1)[tid];
    else if (tid < 64)  ((float4*)W2s)[tid - 32] = ((const float4*)W2)[tid - 32];
    else if (tid < 80)  ((float4*)Ks)[tid - 64]  = ((const float4*)Km)[tid - 64];
    else if (tid < 96)  ((float4*)Ds)[tid - 80]  = ((const float4*)Dm)[tid - 80];
    __syncthreads();

    // ---------------- stage A: h0, dh0 = e0*dz0, a0 = -2*h0*e0*dz0^2 --------------
    {
        const int s = tid >> 4;        // 0..15 sample (intra-half-wave with consumers)
        const int p = tid & 15;        // hidden units 8p..8p+7
        float xr[16];
        #pragma unroll
        for (int q = 0; q < 4; ++q) ((float4*)xr)[q] = ((const float4*)&xt[s * 16])[q];
        const float4 b0a = *(const float4*)&b0[p * 8];
        const float4 b0b = *(const float4*)&b0[p * 8 + 4];
        const float bv[8] = {b0a.x, b0a.y, b0a.z, b0a.w, b0b.x, b0b.y, b0b.z, b0b.w};
        float h0r[8], d0r[8], a0r[8];
        #pragma unroll
        for (int i = 0; i < 8; ++i) {
            const int k = p * 8 + i;
            const float4 wa = ((const float4*)W0)[k * 2];       // global, L1-hot (4KB)
            const float4 wb = ((const float4*)W0)[k * 2 + 1];
            float z = bv[i];
            z = fmaf(wa.x, xr[0], z); z = fmaf(wa.y, xr[1], z);
            z = fmaf(wa.z, xr[2], z); z = fmaf(wa.w, xr[3], z);
            z = fmaf(wb.x, xr[4], z); z = fmaf(wb.y, xr[5], z);
            z = fmaf(wb.z, xr[6], z); z = fmaf(wb.w, xr[7], z);
            float dz = wa.x * xr[8];
            dz = fmaf(wa.y, xr[9],  dz); dz = fmaf(wa.z, xr[10], dz); dz = fmaf(wa.w, xr[11], dz);
            dz = fmaf(wb.x, xr[12], dz); dz = fmaf(wb.y, xr[13], dz);
            dz = fmaf(wb.z, xr[14], dz); dz = fmaf(wb.w, xr[15], dz);
            const float h = tanh_fast(z);
            const float e = fmaf(-h, h, 1.0f);
            h0r[i] = h;
            d0r[i] = e * dz;
            a0r[i] = -2.f * h * e * dz * dz;
        }
        float4* hp = (float4*)&h0s[s * HDIM + p * 8];
        hp[0] = make_float4(h0r[0], h0r[1], h0r[2], h0r[3]);
        hp[1] = make_float4(h0r[4], h0r[5], h0r[6], h0r[7]);
        float4* dp = (float4*)&dh0s[s * HDIM + p * 8];
        dp[0] = make_float4(d0r[0], d0r[1], d0r[2], d0r[3]);
        dp[1] = make_float4(d0r[4], d0r[5], d0r[6], d0r[7]);
        float4* ap = (float4*)&a0s[s * HDIM + p * 8];
        ap[0] = make_float4(a0r[0], a0r[1], a0r[2], a0r[3]);
        ap[1] = make_float4(a0r[4], a0r[5], a0r[6], a0r[7]);
    }
    // no barrier: per-sample rows are produced and consumed within one half-wave;
    // DS ops from a wave complete in program order.

    // thread decomposition for stages B and C
    const int jg  = tid & 31;          // 32 groups x 4 outputs / rows
    const int sgp = tid >> 5;          // 8 groups x 2 samples
    const int s0 = sgp * 2, s1 = s0 + 1;
    const int jbase = jg * 4;

    // ---------------- stage B (transposed axpy): z1 = W1 h0 + b1 ; dz1 = W1 dh0 ---
    float4 az0 = {0,0,0,0}, az1 = {0,0,0,0};
    float4 ad0 = {0,0,0,0}, ad1 = {0,0,0,0};
    {
        const float4* h0p0 = (const float4*)&h0s[s0 * HDIM];
        const float4* h0p1 = (const float4*)&h0s[s1 * HDIM];
        const float4* d0p0 = (const float4*)&dh0s[s0 * HDIM];
        const float4* d0p1 = (const float4*)&dh0s[s1 * HDIM];
        for (int kb = 0; kb < 32; ++kb) {
            const float4 ha = h0p0[kb], hb = h0p1[kb];   // LDS broadcasts
            const float4 da = d0p0[kb], db = d0p1[kb];
            const float hav[4] = {ha.x, ha.y, ha.z, ha.w};
            const float hbv[4] = {hb.x, hb.y, hb.z, hb.w};
            const float dav[4] = {da.x, da.y, da.z, da.w};
            const float dbv[4] = {db.x, db.y, db.z, db.w};
            #pragma unroll
            for (int kk = 0; kk < 4; ++kk) {
                const int k = kb * 4 + kk;
                float4 w;
                if (USE_WT) {
                    w = *(const float4*)&WT[k * HDIM + jbase];   // coalesced 512B/wave
                } else {                                          // slow correct fallback
                    w.x = W1[(jbase + 0) * HDIM + k];
                    w.y = W1[(jbase + 1) * HDIM + k];
                    w.z = W1[(jbase + 2) * HDIM + k];
                    w.w = W1[(jbase + 3) * HDIM + k];
                }
                fma4(az0, w, hav[kk]); fma4(az1, w, hbv[kk]);
                fma4(ad0, w, dav[kk]); fma4(ad1, w, dbv[kk]);
            }
        }
    }

    // stage B epilogue: u1 = w2*e1 -> LDS (alias dh0s); hvv part2
    float* u1s = dh0s;   // dh0s dead after stage B (same half-wave owns its rows)
    float hv0 = 0.f, hv1 = 0.f;
    {
        const float azv0[4] = {az0.x, az0.y, az0.z, az0.w};
        const float azv1[4] = {az1.x, az1.y, az1.z, az1.w};
        const float adv0[4] = {ad0.x, ad0.y, ad0.z, ad0.w};
        const float adv1[4] = {ad1.x, ad1.y, ad1.z, ad1.w};
        float u0v[4], u1v[4];
        #pragma unroll
        for (int jj = 0; jj < 4; ++jj) {
            const int j = jbase + jj;
            const float bb = b1s[j], w2 = W2s[j];
            const float h1a = tanh_fast(azv0[jj] + bb);
            const float e1a = fmaf(-h1a, h1a, 1.f);
            u0v[jj] = w2 * e1a;
            hv0 = fmaf(-2.f * w2 * h1a * e1a, adv0[jj] * adv0[jj], hv0);
            const float h1b = tanh_fast(azv1[jj] + bb);
            const float e1b = fmaf(-h1b, h1b, 1.f);
            u1v[jj] = w2 * e1b;
            hv1 = fmaf(-2.f * w2 * h1b * e1b, adv1[jj] * adv1[jj], hv1);
        }
        *(float4*)&u1s[s0 * HDIM + jbase] = make_float4(u0v[0], u0v[1], u0v[2], u0v[3]);
        *(float4*)&u1s[s1 * HDIM + jbase] = make_float4(u1v[0], u1v[1], u1v[2], u1v[3]);
    }

    // ---------------- stage C: t = W1^T u1 (coalesced W1 rows, u1 via LDS bcast) --
    const int ibase = jbase;
    float4 t0 = {0,0,0,0}, t1 = {0,0,0,0};
    for (int jb = 0; jb < 32; ++jb) {
        const float4 ua4 = *(const float4*)&u1s[s0 * HDIM + jb * 4];  // broadcast
        const float4 ub4 = *(const float4*)&u1s[s1 * HDIM + jb * 4];
        const float uav[4] = {ua4.x, ua4.y, ua4.z, ua4.w};
        const float ubv[4] = {ub4.x, ub4.y, ub4.z, ub4.w};
        #pragma unroll
        for (int jj = 0; jj < 4; ++jj) {
            const int j = jb * 4 + jj;
            const float4 wv = *(const float4*)&W1[j * HDIM + ibase];  // coalesced
            fma4(t0, wv, uav[jj]);
            fma4(t1, wv, ubv[jj]);
        }
    }

    // g partials + hvv part1 = t . a0
    float gp0[8] = {0,0,0,0,0,0,0,0}, gp1[8] = {0,0,0,0,0,0,0,0};
    {
        const float4 h0a4 = *(const float4*)&h0s[s0 * HDIM + ibase];
        const float4 h0b4 = *(const float4*)&h0s[s1 * HDIM + ibase];
        const float4 a0a4 = *(const float4*)&a0s[s0 * HDIM + ibase];
        const float4 a0b4 = *(const float4*)&a0s[s1 * HDIM + ibase];
        const float hav[4] = {h0a4.x, h0a4.y, h0a4.z, h0a4.w};
        const float hbv[4] = {h0b4.x, h0b4.y, h0b4.z, h0b4.w};
        const float aav[4] = {a0a4.x, a0a4.y, a0a4.z, a0a4.w};
        const float abv[4] = {a0b4.x, a0b4.y, a0b4.z, a0b4.w};
        const float t0v[4] = {t0.x, t0.y, t0.z, t0.w};
        const float t1v[4] = {t1.x, t1.y, t1.z, t1.w};
        #pragma unroll
        for (int ii = 0; ii < 4; ++ii) {
            const int i = ibase + ii;
            const float ea = fmaf(-hav[ii], hav[ii], 1.f);
            const float eb = fmaf(-hbv[ii], hbv[ii], 1.f);
            const float u0a = ea * t0v[ii], u0b = eb * t1v[ii];
            hv0 = fmaf(aav[ii], t0v[ii], hv0);
            hv1 = fmaf(abv[ii], t1v[ii], hv1);
            const float4 wa = *(const float4*)&W0[i * 8];       // global, L1-hot
            const float4 wb = *(const float4*)&W0[i * 8 + 4];
            gp0[0] = fmaf(wa.x, u0a, gp0[0]); gp0[1] = fmaf(wa.y, u0a, gp0[1]);
            gp0[2] = fmaf(wa.z, u0a, gp0[2]); gp0[3] = fmaf(wa.w, u0a, gp0[3]);
            gp0[4] = fmaf(wb.x, u0a, gp0[4]); gp0[5] = fmaf(wb.y, u0a, gp0[5]);
            gp0[6] = fmaf(wb.z, u0a, gp0[6]); gp0[7] = fmaf(wb.w, u0a, gp0[7]);
            gp1[0] = fmaf(wa.x, u0b, gp1[0]); gp1[1] = fmaf(wa.y, u0b, gp1[1]);
            gp1[2] = fmaf(wa.z, u0b, gp1[2]); gp1[3] = fmaf(wa.w, u0b, gp1[3]);
            gp1[4] = fmaf(wb.x, u0b, gp1[4]); gp1[5] = fmaf(wb.y, u0b, gp1[5]);
            gp1[6] = fmaf(wb.z, u0b, gp1[6]); gp1[7] = fmaf(wb.w, u0b, gp1[7]);
        }
    }

    // ---------------- reductions (register-light, from v3) ----------------
    #pragma unroll
    for (int m = 1; m <= 16; m <<= 1) {
        hv0 += __shfl_xor(hv0, m);
        hv1 += __shfl_xor(hv1, m);
    }
    #pragma unroll
    for (int m = 8; m <= 16; m <<= 1) {
        #pragma unroll
        for (int d = 0; d < 8; ++d) {
            gp0[d] += __shfl_xor(gp0[d], m);
            gp1[d] += __shfl_xor(gp1[d], m);
        }
    }
    float b0r[4], b1r[4];
    {
        const int hi4 = jg & 4;
        #pragma unroll
        for (int d = 0; d < 4; ++d) {
            const float lo0 = gp0[d]     + __shfl_xor(gp0[d], 4);
            const float hi0 = gp0[d + 4] + __shfl_xor(gp0[d + 4], 4);
            b0r[d] = hi4 ? hi0 : lo0;
            const float lo1 = gp1[d]     + __shfl_xor(gp1[d], 4);
            const float hi1 = gp1[d + 4] + __shfl_xor(gp1[d + 4], 4);
            b1r[d] = hi4 ? hi1 : lo1;
        }
    }
    float c0r[2], c1r[2];
    {
        const int hi2 = jg & 2;
        #pragma unroll
        for (int d = 0; d < 2; ++d) {
            const float lo0 = b0r[d]     + __shfl_xor(b0r[d], 2);
            const float hi0 = b0r[d + 2] + __shfl_xor(b0r[d + 2], 2);
            c0r[d] = hi2 ? hi0 : lo0;
            const float lo1 = b1r[d]     + __shfl_xor(b1r[d], 2);
            const float hi1 = b1r[d + 2] + __shfl_xor(b1r[d + 2], 2);
            c1r[d] = hi2 ? hi1 : lo1;
        }
    }
    float gv0, gv1;
    {
        const int hi1m = jg & 1;
        const float lo0 = c0r[0] + __shfl_xor(c0r[0], 1);
        const float hi0 = c0r[1] + __shfl_xor(c0r[1], 1);
        gv0 = hi1m ? hi0 : lo0;        // total g[jg&7], sample s0
        const float lo1 = c1r[0] + __shfl_xor(c1r[0], 1);
        const float hi1 = c1r[1] + __shfl_xor(c1r[1], 1);
        gv1 = hi1m ? hi1 : lo1;        // sample s1
    }

    // ---------------- force (per-lane row d = jg&7), alpha, output ----------------
    const int dd = jg & 7;
    float fd0, fd1;
    {
        const float* xv0 = &xt[s0 * 16];
        const float* xv1 = &xt[s1 * 16];
        const float* Kr = &Ks[dd * 8];
        const float* Dr = &Ds[dd * 8];
        float a = 0.f, b = 0.f;
        #pragma unroll
        for (int k = 0; k < 8; ++k) {
            a = fmaf(Kr[k], xv0[k], a); a = fmaf(Dr[k], xv0[8 + k], a);
            b = fmaf(Kr[k], xv1[k], b); b = fmaf(Dr[k], xv1[8 + k], b);
        }
        fd0 = -a; fd1 = -b;
    }

    float p0 = gv0 * fd0, q0 = gv0 * gv0;
    float p1 = gv1 * fd1, q1 = gv1 * gv1;
    #pragma unroll
    for (int m = 1; m <= 4; m <<= 1) {
        p0 += __shfl_xor(p0, m); q0 += __shfl_xor(q0, m);
        p1 += __shfl_xor(p1, m); q1 += __shfl_xor(q1, m);
    }
    const float al0 = (p0 + hv0) * __builtin_amdgcn_rcpf(1.f + q0);
    const float al1 = (p1 + hv1) * __builtin_amdgcn_rcpf(1.f + q1);

    if (jg < 16) {                      // lanes 0-7: sample s0; lanes 8-15: sample s1
        const long sm = base + s0 + (jg >> 3);
        const float val = (jg < 8) ? fmaf(-gv0, al0, fd0) : fmaf(-gv1, al1, fd1);
        out[sm * 8 + dd] = val;
    }
}

extern "C" void kernel_launch(void* const* d_in, const int* in_sizes, int n_in,
                              void* d_out, int out_size, void* d_ws, size_t ws_size,
                              hipStream_t stream) {
    const float* X  = (const float*)d_in[0];
    const float* Km = (const float*)d_in[1];
    const float* Dm = (const float*)d_in[2];
    const float* W0 = (const float*)d_in[3];
    const float* b0 = (const float*)d_in[4];
    const float* W1 = (const float*)d_in[5];
    const float* b1 = (const float*)d_in[6];
    const float* W2 = (const float*)d_in[7];
    // d_in[8] = b2 (unused: cancels in grad/hessian/force)
    float* out = (float*)d_out;

    const int BATCH = in_sizes[0] / 16;        // 65536
    const int nblocks = BATCH / S;             // 4096

    const bool use_wt = (ws_size >= (size_t)(HDIM * HDIM * sizeof(float)));
    float* WT = (float*)d_ws;
    if (use_wt) {
        transpose128<<<64, 256, 0, stream>>>(W1, WT);
        dyn_kernel<true><<<nblocks, NT, 0, stream>>>(X, Km, Dm, W0, b0, W1, WT, b1, W2, out);
    } else {
        dyn_kernel<false><<<nblocks, NT, 0, stream>>>(X, Km, Dm, W0, b0, W1, W1, b1, W2, out);
    }
}

// Round 4
// 206.503 us; speedup vs baseline: 2.3002x; 1.1074x over previous
//
#include <hip/hip_runtime.h>
#include <math.h>

#define HDIM 128
#define S 32            // samples per workgroup (v5: doubled to halve W1 L1 traffic/sample)
#define NT 256

// tanh(x) = 1 - 2/(exp(2x)+1): NaN-free for any x, abs err ~1e-7.
__device__ __forceinline__ float tanh_fast(float x){
    const float e = __expf(2.0f * x);
    return 1.0f - 2.0f * __builtin_amdgcn_rcpf(e + 1.0f);
}

__device__ __forceinline__ void fma4(float4& a, const float4 w, const float s){
    a.x = fmaf(w.x, s, a.x); a.y = fmaf(w.y, s, a.y);
    a.z = fmaf(w.z, s, a.z); a.w = fmaf(w.w, s, a.w);
}

// Prep: WT[k][j] = W1[j][k]
__global__ void transpose128(const float* __restrict__ W1, float* __restrict__ WT){
    const int idx = blockIdx.x * 256 + threadIdx.x;   // coalesced read
    WT[(idx & 127) * HDIM + (idx >> 7)] = W1[idx];
}

// v5: S=16 -> 32. W1/WT bytes per block are constant, so per-sample L1 traffic halves
// and stage-B/C arithmetic intensity doubles (32 fma per 16B load). LDS kept at 36KB
// (4 blocks/CU) by dropping a0s: each lane snapshots its own h0/dh0 chunk (ibase==jbase)
// before u1 overwrites dh0s, reconstructing a0 = -2*h0*dh0^2/e0 in registers.
// Per-wave sample ownership preserved -> still ONE barrier.
template<bool USE_WT>
__global__ __launch_bounds__(NT, 4)
void dyn_kernel(const float* __restrict__ X, const float* __restrict__ Km,
                const float* __restrict__ Dm, const float* __restrict__ W0,
                const float* __restrict__ b0, const float* __restrict__ W1,
                const float* __restrict__ WT, const float* __restrict__ b1,
                const float* __restrict__ W2, float* __restrict__ out)
{
    __shared__ float xt[S * 16];            // 2 KB
    __shared__ float b1s[HDIM], W2s[HDIM];  // 1 KB
    __shared__ float Ks[64], Ds[64];        // 0.5 KB
    __shared__ float h0s[S * HDIM];         // 16 KB
    __shared__ float dh0s[S * HDIM];        // 16 KB (aliased as u1s after stage B)

    const int tid = threadIdx.x;
    const long base = (long)blockIdx.x * S;

    // ---------------- load X tile + small weights (ONLY barrier) ----------------
    if (tid < 128) ((float4*)xt)[tid] = ((const float4*)(X + base * 16))[tid];
    if (tid < 32)       ((float4*)b1s)[tid]      = ((const float4*)b1)[tid];
    else if (tid < 64)  ((float4*)W2s)[tid - 32] = ((const float4*)W2)[tid - 32];
    else if (tid < 80)  ((float4*)Ks)[tid - 64]  = ((const float4*)Km)[tid - 64];
    else if (tid < 96)  ((float4*)Ds)[tid - 80]  = ((const float4*)Dm)[tid - 80];
    __syncthreads();

    // ---------------- stage A: h0, dh0 = e0*dz0 (8 threads/sample, 16 units each) --
    {
        const int s = tid >> 3;        // 0..31 sample  (wave w owns samples 8w..8w+7)
        const int p = tid & 7;         // hidden units p*16 .. p*16+15
        float xr[16], bv[16];
        #pragma unroll
        for (int q = 0; q < 4; ++q) {
            ((float4*)xr)[q] = ((const float4*)&xt[s * 16])[q];
            ((float4*)bv)[q] = ((const float4*)b0)[p * 4 + q];   // global, L1-hot
        }
        float h0r[16], d0r[16];
        #pragma unroll
        for (int i = 0; i < 16; ++i) {
            const int k = p * 16 + i;
            const float4 wa = ((const float4*)W0)[k * 2];        // global, L1-hot (4KB)
            const float4 wb = ((const float4*)W0)[k * 2 + 1];
            float z = bv[i];
            z = fmaf(wa.x, xr[0], z); z = fmaf(wa.y, xr[1], z);
            z = fmaf(wa.z, xr[2], z); z = fmaf(wa.w, xr[3], z);
            z = fmaf(wb.x, xr[4], z); z = fmaf(wb.y, xr[5], z);
            z = fmaf(wb.z, xr[6], z); z = fmaf(wb.w, xr[7], z);
            float dz = wa.x * xr[8];
            dz = fmaf(wa.y, xr[9],  dz); dz = fmaf(wa.z, xr[10], dz); dz = fmaf(wa.w, xr[11], dz);
            dz = fmaf(wb.x, xr[12], dz); dz = fmaf(wb.y, xr[13], dz);
            dz = fmaf(wb.z, xr[14], dz); dz = fmaf(wb.w, xr[15], dz);
            const float h = tanh_fast(z);
            const float e = fmaf(-h, h, 1.0f);
            h0r[i] = h;
            d0r[i] = e * dz;
        }
        float4* hp = (float4*)&h0s[s * HDIM + p * 16];
        float4* dp = (float4*)&dh0s[s * HDIM + p * 16];
        #pragma unroll
        for (int q = 0; q < 4; ++q) {
            hp[q] = make_float4(h0r[q*4], h0r[q*4+1], h0r[q*4+2], h0r[q*4+3]);
            dp[q] = make_float4(d0r[q*4], d0r[q*4+1], d0r[q*4+2], d0r[q*4+3]);
        }
    }
    // no barrier: each wave produced exactly the 8 sample-rows it consumes below;
    // DS ops from a wave complete in program order.

    // thread decomposition for stages B and C
    const int jg  = tid & 31;          // 32 groups x 4 outputs / rows (jbase == ibase)
    const int sgp = tid >> 5;          // 8 groups x 4 samples
    const int sb  = sgp * 4;
    const int jbase = jg * 4;

    // ---------------- stage B (transposed axpy): z1 = W1 h0 + b1 ; dz1 = W1 dh0 ---
    float4 az[4] = {{0,0,0,0},{0,0,0,0},{0,0,0,0},{0,0,0,0}};
    float4 ad[4] = {{0,0,0,0},{0,0,0,0},{0,0,0,0},{0,0,0,0}};
    for (int kb = 0; kb < 32; ++kb) {
        float he[4][4], de[4][4];
        #pragma unroll
        for (int q = 0; q < 4; ++q) {
            const float4 h4 = *(const float4*)&h0s[(sb + q) * HDIM + kb * 4];
            he[q][0] = h4.x; he[q][1] = h4.y; he[q][2] = h4.z; he[q][3] = h4.w;
            const float4 d4 = *(const float4*)&dh0s[(sb + q) * HDIM + kb * 4];
            de[q][0] = d4.x; de[q][1] = d4.y; de[q][2] = d4.z; de[q][3] = d4.w;
        }
        #pragma unroll
        for (int kk = 0; kk < 4; ++kk) {
            const int k = kb * 4 + kk;
            float4 w;
            if (USE_WT) {
                w = *(const float4*)&WT[k * HDIM + jbase];        // coalesced 512B/wave
            } else {                                              // slow correct fallback
                w.x = W1[(jbase + 0) * HDIM + k];
                w.y = W1[(jbase + 1) * HDIM + k];
                w.z = W1[(jbase + 2) * HDIM + k];
                w.w = W1[(jbase + 3) * HDIM + k];
            }
            #pragma unroll
            for (int q = 0; q < 4; ++q) {
                fma4(az[q], w, he[q][kk]);
                fma4(ad[q], w, de[q][kk]);
            }
        }
    }

    // ---- stage B epilogue: per sample q: u1 -> LDS (alias dh0s), hvv part2,
    //      snapshot own h0/dh0 chunk (i = jbase..jbase+3) BEFORE the overwrite. ----
    float* u1s = dh0s;
    float hv[4] = {0.f, 0.f, 0.f, 0.f};
    float e0v[4][4], a0v[4][4];
    {
        const float4 b14 = *(const float4*)&b1s[jbase];
        const float4 w24 = *(const float4*)&W2s[jbase];
        const float bbv[4] = {b14.x, b14.y, b14.z, b14.w};
        const float w2v[4] = {w24.x, w24.y, w24.z, w24.w};
        #pragma unroll
        for (int q = 0; q < 4; ++q) {
            const float azv[4] = {az[q].x, az[q].y, az[q].z, az[q].w};
            const float adv[4] = {ad[q].x, ad[q].y, ad[q].z, ad[q].w};
            float uv[4];
            #pragma unroll
            for (int jj = 0; jj < 4; ++jj) {
                const float h1 = tanh_fast(azv[jj] + bbv[jj]);
                const float e1 = fmaf(-h1, h1, 1.f);
                uv[jj] = w2v[jj] * e1;
                hv[q] = fmaf(-2.f * w2v[jj] * h1 * e1, adv[jj] * adv[jj], hv[q]);
            }
            // snapshot own chunk of h0/dh0 (the only part this lane needs later)
            const float4 h04 = *(const float4*)&h0s[(sb + q) * HDIM + jbase];
            const float4 d04 = *(const float4*)&dh0s[(sb + q) * HDIM + jbase];
            const float hh[4] = {h04.x, h04.y, h04.z, h04.w};
            const float dh[4] = {d04.x, d04.y, d04.z, d04.w};
            #pragma unroll
            for (int ii = 0; ii < 4; ++ii) {
                const float e0 = fmaf(-hh[ii], hh[ii], 1.f);
                e0v[q][ii] = e0;
                // a0 = -2*h0*e0*dz0^2 = -2*h0*dh0^2/e0
                a0v[q][ii] = -2.f * hh[ii] * dh[ii] * dh[ii]
                             * __builtin_amdgcn_rcpf(fmaxf(e0, 1e-20f));
            }
            // overwrite AFTER the snapshot read (same-wave DS program order)
            *(float4*)&u1s[(sb + q) * HDIM + jbase] = make_float4(uv[0], uv[1], uv[2], uv[3]);
        }
    }

    // ---------------- stage C: t = W1^T u1 (coalesced W1 rows, u1 via LDS bcast) --
    float4 t[4] = {{0,0,0,0},{0,0,0,0},{0,0,0,0},{0,0,0,0}};
    for (int jb = 0; jb < 32; ++jb) {
        float ue[4][4];
        #pragma unroll
        for (int q = 0; q < 4; ++q) {
            const float4 u4 = *(const float4*)&u1s[(sb + q) * HDIM + jb * 4];
            ue[q][0] = u4.x; ue[q][1] = u4.y; ue[q][2] = u4.z; ue[q][3] = u4.w;
        }
        #pragma unroll
        for (int jj = 0; jj < 4; ++jj) {
            const int j = jb * 4 + jj;
            const float4 wv = *(const float4*)&W1[j * HDIM + jbase];  // coalesced
            #pragma unroll
            for (int q = 0; q < 4; ++q) fma4(t[q], wv, ue[q][jj]);
        }
    }

    // g partials + hvv part1 = t . a0  (W0 rows hoisted out of the sample loop)
    float gp[4][8];
    #pragma unroll
    for (int q = 0; q < 4; ++q)
        #pragma unroll
        for (int d = 0; d < 8; ++d) gp[q][d] = 0.f;
    {
        const float tv[4][4] = {
            {t[0].x, t[0].y, t[0].z, t[0].w}, {t[1].x, t[1].y, t[1].z, t[1].w},
            {t[2].x, t[2].y, t[2].z, t[2].w}, {t[3].x, t[3].y, t[3].z, t[3].w}};
        #pragma unroll
        for (int ii = 0; ii < 4; ++ii) {
            const int i = jbase + ii;
            const float4 wa = *(const float4*)&W0[i * 8];       // global, L1-hot
            const float4 wb = *(const float4*)&W0[i * 8 + 4];
            #pragma unroll
            for (int q = 0; q < 4; ++q) {
                const float u0 = e0v[q][ii] * tv[q][ii];
                hv[q] = fmaf(a0v[q][ii], tv[q][ii], hv[q]);
                gp[q][0] = fmaf(wa.x, u0, gp[q][0]); gp[q][1] = fmaf(wa.y, u0, gp[q][1]);
                gp[q][2] = fmaf(wa.z, u0, gp[q][2]); gp[q][3] = fmaf(wa.w, u0, gp[q][3]);
                gp[q][4] = fmaf(wb.x, u0, gp[q][4]); gp[q][5] = fmaf(wb.y, u0, gp[q][5]);
                gp[q][6] = fmaf(wb.z, u0, gp[q][6]); gp[q][7] = fmaf(wb.w, u0, gp[q][7]);
            }
        }
    }

    // ---------------- reductions (register-light folding butterflies) -------------
    #pragma unroll
    for (int m = 1; m <= 16; m <<= 1) {
        #pragma unroll
        for (int q = 0; q < 4; ++q) hv[q] += __shfl_xor(hv[q], m);
    }
    #pragma unroll
    for (int m = 8; m <= 16; m <<= 1) {
        #pragma unroll
        for (int q = 0; q < 4; ++q)
            #pragma unroll
            for (int d = 0; d < 8; ++d) gp[q][d] += __shfl_xor(gp[q][d], m);
    }
    float bq[4][4];
    {
        const int hi4 = jg & 4;
        #pragma unroll
        for (int q = 0; q < 4; ++q)
            #pragma unroll
            for (int d = 0; d < 4; ++d) {
                const float lo = gp[q][d]     + __shfl_xor(gp[q][d], 4);
                const float hi = gp[q][d + 4] + __shfl_xor(gp[q][d + 4], 4);
                bq[q][d] = hi4 ? hi : lo;
            }
    }
    float cq[4][2];
    {
        const int hi2 = jg & 2;
        #pragma unroll
        for (int q = 0; q < 4; ++q)
            #pragma unroll
            for (int d = 0; d < 2; ++d) {
                const float lo = bq[q][d]     + __shfl_xor(bq[q][d], 2);
                const float hi = bq[q][d + 2] + __shfl_xor(bq[q][d + 2], 2);
                cq[q][d] = hi2 ? hi : lo;
            }
    }
    float gv[4];
    {
        const int hi1m = jg & 1;
        #pragma unroll
        for (int q = 0; q < 4; ++q) {
            const float lo = cq[q][0] + __shfl_xor(cq[q][0], 1);
            const float hi = cq[q][1] + __shfl_xor(cq[q][1], 1);
            gv[q] = hi1m ? hi : lo;    // total g[jg&7] for sample sb+q
        }
    }

    // ---------------- force (per-lane row d = jg&7), alpha, output ----------------
    const int dd = jg & 7;
    float fd[4];
    {
        const float* Kr = &Ks[dd * 8];
        const float* Dr = &Ds[dd * 8];
        #pragma unroll
        for (int q = 0; q < 4; ++q) {
            const float* xv = &xt[(sb + q) * 16];
            float a = 0.f;
            #pragma unroll
            for (int k = 0; k < 8; ++k) {
                a = fmaf(Kr[k], xv[k], a);
                a = fmaf(Dr[k], xv[8 + k], a);
            }
            fd[q] = -a;
        }
    }

    float po[4], qo[4];
    #pragma unroll
    for (int q = 0; q < 4; ++q) { po[q] = gv[q] * fd[q]; qo[q] = gv[q] * gv[q]; }
    #pragma unroll
    for (int m = 1; m <= 4; m <<= 1)
        #pragma unroll
        for (int q = 0; q < 4; ++q) {
            po[q] += __shfl_xor(po[q], m);
            qo[q] += __shfl_xor(qo[q], m);
        }

    const int qs = jg >> 3;            // which of my 4 samples this lane outputs
    float val = 0.f;
    #pragma unroll
    for (int q = 0; q < 4; ++q) {
        if (q == qs) {
            const float al = (po[q] + hv[q]) * __builtin_amdgcn_rcpf(1.f + qo[q]);
            val = fmaf(-gv[q], al, fd[q]);
        }
    }
    out[base * 8 + tid] = val;         // fully coalesced: index == base*8 + sgp*32 + jg
}

extern "C" void kernel_launch(void* const* d_in, const int* in_sizes, int n_in,
                              void* d_out, int out_size, void* d_ws, size_t ws_size,
                              hipStream_t stream) {
    const float* X  = (const float*)d_in[0];
    const float* Km = (const float*)d_in[1];
    const float* Dm = (const float*)d_in[2];
    const float* W0 = (const float*)d_in[3];
    const float* b0 = (const float*)d_in[4];
    const float* W1 = (const float*)d_in[5];
    const float* b1 = (const float*)d_in[6];
    const float* W2 = (const float*)d_in[7];
    // d_in[8] = b2 (unused: cancels in grad/hessian/force)
    float* out = (float*)d_out;

    const int BATCH = in_sizes[0] / 16;        // 65536
    const int nblocks = BATCH / S;             // 2048

    const bool use_wt = (ws_size >= (size_t)(HDIM * HDIM * sizeof(float)));
    float* WT = (float*)d_ws;
    if (use_wt) {
        transpose128<<<64, 256, 0, stream>>>(W1, WT);
        dyn_kernel<true><<<nblocks, NT, 0, stream>>>(X, Km, Dm, W0, b0, W1, WT, b1, W2, out);
    } else {
        dyn_kernel<false><<<nblocks, NT, 0, stream>>>(X, Km, Dm, W0, b0, W1, W1, b1, W2, out);
    }
}

// Round 5
// 204.832 us; speedup vs baseline: 2.3190x; 1.0082x over previous
//
#include <hip/hip_runtime.h>
#include <math.h>

#define HDIM 128
#define S 32            // samples per workgroup
#define NT 256

// tanh(x) = 1 - 2/(exp(2x)+1): NaN-free for any x, abs err ~1e-7.
__device__ __forceinline__ float tanh_fast(float x){
    const float e = __expf(2.0f * x);
    return 1.0f - 2.0f * __builtin_amdgcn_rcpf(e + 1.0f);
}

__device__ __forceinline__ void fma4(float4& a, const float4 w, const float s){
    a.x = fmaf(w.x, s, a.x); a.y = fmaf(w.y, s, a.y);
    a.z = fmaf(w.z, s, a.z); a.w = fmaf(w.w, s, a.w);
}

// Prep: WT[k][j] = W1[j][k]
__global__ void transpose128(const float* __restrict__ W1, float* __restrict__ WT){
    const int idx = blockIdx.x * 256 + threadIdx.x;   // coalesced read
    WT[(idx & 127) * HDIM + (idx >> 7)] = W1[idx];
}

// v6: v5 algorithm with the spill fixed.
//  - __launch_bounds__(NT,2): the allocator's empirical budget tracks 256/min_waves
//    ((NT,5)->48, (NT,4)->56..64 across v2-v5); at 4 samples/thread demand is ~100
//    regs, so (NT,4) spilled ~25 regs -> 60 MB/dispatch scratch = v5's WRITE_SIZE 51MB.
//    (NT,2) -> budget ~128. HW occupancy unchanged: LDS caps 4 blocks/CU = 16 waves/CU,
//    and <=128 VGPR still allows 4 waves/SIMD.
//  - e0v snapshot dropped (-16 live regs): h0s is never overwritten, stage C reloads
//    h0 from LDS and recomputes e0; only a0v is carried in registers.
//  - ZERO barriers: X tile staged per-wave (wave w owns samples 8w..8w+7 end-to-end);
//    b1/W2/K/D read from global (L1-hot). Waves fully independent.
template<bool USE_WT>
__global__ __launch_bounds__(NT, 2)
void dyn_kernel(const float* __restrict__ X, const float* __restrict__ Km,
                const float* __restrict__ Dm, const float* __restrict__ W0,
                const float* __restrict__ b0, const float* __restrict__ W1,
                const float* __restrict__ WT, const float* __restrict__ b1,
                const float* __restrict__ W2, float* __restrict__ out)
{
    __shared__ float xt[S * 16];            // 2 KB  (per-wave staged)
    __shared__ float h0s[S * HDIM];         // 16 KB
    __shared__ float dh0s[S * HDIM];        // 16 KB (aliased as u1s after stage B)

    const int tid  = threadIdx.x;
    const int lane = tid & 63;
    const int wv   = tid >> 6;              // wave id 0..3; owns samples 8wv..8wv+7
    const long base = (long)blockIdx.x * S;

    // ---------------- per-wave X staging (NO barrier anywhere) -------------------
    if (lane < 32)
        ((float4*)xt)[wv * 32 + lane] = ((const float4*)(X + base * 16))[wv * 32 + lane];
    // same-wave DS program order makes this visible to the wave's own stage A.

    // ---------------- stage A: h0, dh0 = e0*dz0 (8 threads/sample, 16 units) ------
    {
        const int s = tid >> 3;        // 0..31 sample (within this wave's 8)
        const int p = tid & 7;         // hidden units p*16 .. p*16+15
        float xr[16], bv[16];
        #pragma unroll
        for (int q = 0; q < 4; ++q) {
            ((float4*)xr)[q] = ((const float4*)&xt[s * 16])[q];
            ((float4*)bv)[q] = ((const float4*)b0)[p * 4 + q];   // global, L1-hot
        }
        float h0r[16], d0r[16];
        #pragma unroll
        for (int i = 0; i < 16; ++i) {
            const int k = p * 16 + i;
            const float4 wa = ((const float4*)W0)[k * 2];        // global, L1-hot (4KB)
            const float4 wb = ((const float4*)W0)[k * 2 + 1];
            float z = bv[i];
            z = fmaf(wa.x, xr[0], z); z = fmaf(wa.y, xr[1], z);
            z = fmaf(wa.z, xr[2], z); z = fmaf(wa.w, xr[3], z);
            z = fmaf(wb.x, xr[4], z); z = fmaf(wb.y, xr[5], z);
            z = fmaf(wb.z, xr[6], z); z = fmaf(wb.w, xr[7], z);
            float dz = wa.x * xr[8];
            dz = fmaf(wa.y, xr[9],  dz); dz = fmaf(wa.z, xr[10], dz); dz = fmaf(wa.w, xr[11], dz);
            dz = fmaf(wb.x, xr[12], dz); dz = fmaf(wb.y, xr[13], dz);
            dz = fmaf(wb.z, xr[14], dz); dz = fmaf(wb.w, xr[15], dz);
            const float h = tanh_fast(z);
            const float e = fmaf(-h, h, 1.0f);
            h0r[i] = h;
            d0r[i] = e * dz;
        }
        float4* hp = (float4*)&h0s[s * HDIM + p * 16];
        float4* dp = (float4*)&dh0s[s * HDIM + p * 16];
        #pragma unroll
        for (int q = 0; q < 4; ++q) {
            hp[q] = make_float4(h0r[q*4], h0r[q*4+1], h0r[q*4+2], h0r[q*4+3]);
            dp[q] = make_float4(d0r[q*4], d0r[q*4+1], d0r[q*4+2], d0r[q*4+3]);
        }
    }
    // no barrier: wave w produced exactly the 8 sample-rows it consumes below.

    // thread decomposition for stages B and C
    const int jg  = tid & 31;          // 32 groups x 4 outputs / rows (jbase == ibase)
    const int sgp = tid >> 5;          // 8 groups x 4 samples
    const int sb  = sgp * 4;
    const int jbase = jg * 4;

    // ---------------- stage B (transposed axpy): z1 = W1 h0 + b1 ; dz1 = W1 dh0 ---
    float4 az[4] = {{0,0,0,0},{0,0,0,0},{0,0,0,0},{0,0,0,0}};
    float4 ad[4] = {{0,0,0,0},{0,0,0,0},{0,0,0,0},{0,0,0,0}};
    for (int kb = 0; kb < 32; ++kb) {
        float he[4][4], de[4][4];
        #pragma unroll
        for (int q = 0; q < 4; ++q) {
            const float4 h4 = *(const float4*)&h0s[(sb + q) * HDIM + kb * 4];
            he[q][0] = h4.x; he[q][1] = h4.y; he[q][2] = h4.z; he[q][3] = h4.w;
            const float4 d4 = *(const float4*)&dh0s[(sb + q) * HDIM + kb * 4];
            de[q][0] = d4.x; de[q][1] = d4.y; de[q][2] = d4.z; de[q][3] = d4.w;
        }
        #pragma unroll
        for (int kk = 0; kk < 4; ++kk) {
            const int k = kb * 4 + kk;
            float4 w;
            if (USE_WT) {
                w = *(const float4*)&WT[k * HDIM + jbase];        // coalesced 512B/wave
            } else {                                              // slow correct fallback
                w.x = W1[(jbase + 0) * HDIM + k];
                w.y = W1[(jbase + 1) * HDIM + k];
                w.z = W1[(jbase + 2) * HDIM + k];
                w.w = W1[(jbase + 3) * HDIM + k];
            }
            #pragma unroll
            for (int q = 0; q < 4; ++q) {
                fma4(az[q], w, he[q][kk]);
                fma4(ad[q], w, de[q][kk]);
            }
        }
    }

    // ---- stage B epilogue: per sample q: u1 -> LDS (alias dh0s), hvv part2,
    //      snapshot a0 (own chunk i = jbase..+3) BEFORE the overwrite. ------------
    float* u1s = dh0s;
    float hv[4] = {0.f, 0.f, 0.f, 0.f};
    float a0v[4][4];
    {
        const float4 b14 = *(const float4*)&b1[jbase];            // global, L1-hot
        const float4 w24 = *(const float4*)&W2[jbase];
        const float bbv[4] = {b14.x, b14.y, b14.z, b14.w};
        const float w2v[4] = {w24.x, w24.y, w24.z, w24.w};
        #pragma unroll
        for (int q = 0; q < 4; ++q) {
            const float azv[4] = {az[q].x, az[q].y, az[q].z, az[q].w};
            const float adv[4] = {ad[q].x, ad[q].y, ad[q].z, ad[q].w};
            float uv[4];
            #pragma unroll
            for (int jj = 0; jj < 4; ++jj) {
                const float h1 = tanh_fast(azv[jj] + bbv[jj]);
                const float e1 = fmaf(-h1, h1, 1.f);
                uv[jj] = w2v[jj] * e1;
                hv[q] = fmaf(-2.f * w2v[jj] * h1 * e1, adv[jj] * adv[jj], hv[q]);
            }
            // snapshot own chunk: a0 = -2*h0*e0*dz0^2 = -2*h0*dh0^2/e0
            const float4 h04 = *(const float4*)&h0s[(sb + q) * HDIM + jbase];
            const float4 d04 = *(const float4*)&dh0s[(sb + q) * HDIM + jbase];
            const float hh[4] = {h04.x, h04.y, h04.z, h04.w};
            const float dh[4] = {d04.x, d04.y, d04.z, d04.w};
            #pragma unroll
            for (int ii = 0; ii < 4; ++ii) {
                const float e0 = fmaf(-hh[ii], hh[ii], 1.f);
                a0v[q][ii] = -2.f * hh[ii] * dh[ii] * dh[ii]
                             * __builtin_amdgcn_rcpf(fmaxf(e0, 1e-20f));
            }
            // overwrite AFTER the snapshot read (same-wave DS program order)
            *(float4*)&u1s[(sb + q) * HDIM + jbase] = make_float4(uv[0], uv[1], uv[2], uv[3]);
        }
    }

    // ---------------- stage C: t = W1^T u1 (coalesced W1 rows, u1 via LDS bcast) --
    float4 t[4] = {{0,0,0,0},{0,0,0,0},{0,0,0,0},{0,0,0,0}};
    for (int jb = 0; jb < 32; ++jb) {
        float ue[4][4];
        #pragma unroll
        for (int q = 0; q < 4; ++q) {
            const float4 u4 = *(const float4*)&u1s[(sb + q) * HDIM + jb * 4];
            ue[q][0] = u4.x; ue[q][1] = u4.y; ue[q][2] = u4.z; ue[q][3] = u4.w;
        }
        #pragma unroll
        for (int jj = 0; jj < 4; ++jj) {
            const int j = jb * 4 + jj;
            const float4 wvv = *(const float4*)&W1[j * HDIM + jbase];  // coalesced
            #pragma unroll
            for (int q = 0; q < 4; ++q) fma4(t[q], wvv, ue[q][jj]);
        }
    }

    // g partials + hvv part1 = t . a0 ; e0 recomputed from h0s (still intact)
    float gp[4][8];
    #pragma unroll
    for (int q = 0; q < 4; ++q)
        #pragma unroll
        for (int d = 0; d < 8; ++d) gp[q][d] = 0.f;
    {
        const float tv[4][4] = {
            {t[0].x, t[0].y, t[0].z, t[0].w}, {t[1].x, t[1].y, t[1].z, t[1].w},
            {t[2].x, t[2].y, t[2].z, t[2].w}, {t[3].x, t[3].y, t[3].z, t[3].w}};
        float e0r[4][4];
        #pragma unroll
        for (int q = 0; q < 4; ++q) {
            const float4 h04 = *(const float4*)&h0s[(sb + q) * HDIM + jbase];
            e0r[q][0] = fmaf(-h04.x, h04.x, 1.f);
            e0r[q][1] = fmaf(-h04.y, h04.y, 1.f);
            e0r[q][2] = fmaf(-h04.z, h04.z, 1.f);
            e0r[q][3] = fmaf(-h04.w, h04.w, 1.f);
        }
        #pragma unroll
        for (int ii = 0; ii < 4; ++ii) {
            const int i = jbase + ii;
            const float4 wa = *(const float4*)&W0[i * 8];       // global, L1-hot
            const float4 wb = *(const float4*)&W0[i * 8 + 4];
            #pragma unroll
            for (int q = 0; q < 4; ++q) {
                const float u0 = e0r[q][ii] * tv[q][ii];
                hv[q] = fmaf(a0v[q][ii], tv[q][ii], hv[q]);
                gp[q][0] = fmaf(wa.x, u0, gp[q][0]); gp[q][1] = fmaf(wa.y, u0, gp[q][1]);
                gp[q][2] = fmaf(wa.z, u0, gp[q][2]); gp[q][3] = fmaf(wa.w, u0, gp[q][3]);
                gp[q][4] = fmaf(wb.x, u0, gp[q][4]); gp[q][5] = fmaf(wb.y, u0, gp[q][5]);
                gp[q][6] = fmaf(wb.z, u0, gp[q][6]); gp[q][7] = fmaf(wb.w, u0, gp[q][7]);
            }
        }
    }

    // ---------------- reductions (register-light folding butterflies) -------------
    #pragma unroll
    for (int m = 1; m <= 16; m <<= 1) {
        #pragma unroll
        for (int q = 0; q < 4; ++q) hv[q] += __shfl_xor(hv[q], m);
    }
    #pragma unroll
    for (int m = 8; m <= 16; m <<= 1) {
        #pragma unroll
        for (int q = 0; q < 4; ++q)
            #pragma unroll
            for (int d = 0; d < 8; ++d) gp[q][d] += __shfl_xor(gp[q][d], m);
    }
    float bq[4][4];
    {
        const int hi4 = jg & 4;
        #pragma unroll
        for (int q = 0; q < 4; ++q)
            #pragma unroll
            for (int d = 0; d < 4; ++d) {
                const float lo = gp[q][d]     + __shfl_xor(gp[q][d], 4);
                const float hi = gp[q][d + 4] + __shfl_xor(gp[q][d + 4], 4);
                bq[q][d] = hi4 ? hi : lo;
            }
    }
    float cq[4][2];
    {
        const int hi2 = jg & 2;
        #pragma unroll
        for (int q = 0; q < 4; ++q)
            #pragma unroll
            for (int d = 0; d < 2; ++d) {
                const float lo = bq[q][d]     + __shfl_xor(bq[q][d], 2);
                const float hi = bq[q][d + 2] + __shfl_xor(bq[q][d + 2], 2);
                cq[q][d] = hi2 ? hi : lo;
            }
    }
    float gv[4];
    {
        const int hi1m = jg & 1;
        #pragma unroll
        for (int q = 0; q < 4; ++q) {
            const float lo = cq[q][0] + __shfl_xor(cq[q][0], 1);
            const float hi = cq[q][1] + __shfl_xor(cq[q][1], 1);
            gv[q] = hi1m ? hi : lo;    // total g[jg&7] for sample sb+q
        }
    }

    // ---------------- force (per-lane row d = jg&7), alpha, output ----------------
    const int dd = jg & 7;
    float fd[4];
    {
        const float* Kr = &Km[dd * 8];     // global, L1-hot broadcast
        const float* Dr = &Dm[dd * 8];
        float kr[8], dr[8];
        #pragma unroll
        for (int k = 0; k < 8; ++k) { kr[k] = Kr[k]; dr[k] = Dr[k]; }
        #pragma unroll
        for (int q = 0; q < 4; ++q) {
            const float* xv = &xt[(sb + q) * 16];
            float a = 0.f;
            #pragma unroll
            for (int k = 0; k < 8; ++k) {
                a = fmaf(kr[k], xv[k], a);
                a = fmaf(dr[k], xv[8 + k], a);
            }
            fd[q] = -a;
        }
    }

    float po[4], qo[4];
    #pragma unroll
    for (int q = 0; q < 4; ++q) { po[q] = gv[q] * fd[q]; qo[q] = gv[q] * gv[q]; }
    #pragma unroll
    for (int m = 1; m <= 4; m <<= 1)
        #pragma unroll
        for (int q = 0; q < 4; ++q) {
            po[q] += __shfl_xor(po[q], m);
            qo[q] += __shfl_xor(qo[q], m);
        }

    const int qs = jg >> 3;            // which of my 4 samples this lane outputs
    float val = 0.f;
    #pragma unroll
    for (int q = 0; q < 4; ++q) {
        if (q == qs) {
            const float al = (po[q] + hv[q]) * __builtin_amdgcn_rcpf(1.f + qo[q]);
            val = fmaf(-gv[q], al, fd[q]);
        }
    }
    out[base * 8 + tid] = val;         // fully coalesced

}

extern "C" void kernel_launch(void* const* d_in, const int* in_sizes, int n_in,
                              void* d_out, int out_size, void* d_ws, size_t ws_size,
                              hipStream_t stream) {
    const float* X  = (const float*)d_in[0];
    const float* Km = (const float*)d_in[1];
    const float* Dm = (const float*)d_in[2];
    const float* W0 = (const float*)d_in[3];
    const float* b0 = (const float*)d_in[4];
    const float* W1 = (const float*)d_in[5];
    const float* b1 = (const float*)d_in[6];
    const float* W2 = (const float*)d_in[7];
    // d_in[8] = b2 (unused: cancels in grad/hessian/force)
    float* out = (float*)d_out;

    const int BATCH = in_sizes[0] / 16;        // 65536
    const int nblocks = BATCH / S;             // 2048

    const bool use_wt = (ws_size >= (size_t)(HDIM * HDIM * sizeof(float)));
    float* WT = (float*)d_ws;
    if (use_wt) {
        transpose128<<<64, 256, 0, stream>>>(W1, WT);
        dyn_kernel<true><<<nblocks, NT, 0, stream>>>(X, Km, Dm, W0, b0, W1, WT, b1, W2, out);
    } else {
        dyn_kernel<false><<<nblocks, NT, 0, stream>>>(X, Km, Dm, W0, b0, W1, W1, b1, W2, out);
    }
}

// Round 6
// 141.921 us; speedup vs baseline: 3.3469x; 1.4433x over previous
//
#include <hip/hip_runtime.h>
#include <math.h>

#define HDIM 128
#define S 16            // samples per workgroup
#define NT 256
#define ASTR 136        // bf16 row stride (+8 pad -> 2-way-max LDS bank aliasing)

typedef __attribute__((ext_vector_type(8))) short  bf16x8;   // MFMA A/B frag (guide-verified)
typedef __attribute__((ext_vector_type(8))) unsigned short u16x8;
typedef __attribute__((ext_vector_type(4))) float  f32x4;    // MFMA C/D frag

// tanh(x) = 1 - 2/(exp(2x)+1): NaN-free for any x, abs err ~1e-7.
__device__ __forceinline__ float tanh_fast(float x){
    const float e = __expf(2.0f * x);
    return 1.0f - 2.0f * __builtin_amdgcn_rcpf(e + 1.0f);
}
// bf16 split helpers: v ~= hi + lo, |err| <~ 2^-17 |v|
__device__ __forceinline__ unsigned short bhi(float v){
    return (unsigned short)(__float_as_uint(v) >> 16);
}
__device__ __forceinline__ unsigned short brne(float v){
    unsigned u = __float_as_uint(v);
    return (unsigned short)((u + 0x7FFFu + ((u >> 16) & 1u)) >> 16);
}
__device__ __forceinline__ float bf(unsigned short u){
    return __uint_as_float(((unsigned)u) << 16);
}

// ---------------- prep: pack W1 into B-fragment order, hi/lo bf16 ----------------
// frag index t = ((nt*4+ks)*64 + lane)*8 + r ; lane: m=lane>>4, c=lane&15
//   stage-B operand: B[k][j] = W1[j][k], j = nt*16+c, k = ks*32+m*8+r
//   stage-C operand: B[k][i] = W1[k][i], i = nt*16+c, same k
// ws layout (ushort): [0]=BhB [16384]=BlB [32768]=BhC [49152]=BlC  (128 KiB total)
__global__ void prep_frags(const float* __restrict__ W1, unsigned short* __restrict__ ws){
    const int t = blockIdx.x * 256 + threadIdx.x;          // 0..16383
    const int r = t & 7, l = (t >> 3) & 63, tile = t >> 9;
    const int nt = tile >> 2, ks = tile & 3;
    const int m = l >> 4, c = l & 15;
    const int k = ks * 32 + m * 8 + r;
    {
        const float v = W1[(nt * 16 + c) * HDIM + k];      // W1^T orientation
        const unsigned short hi = bhi(v);
        ws[t]          = hi;
        ws[16384 + t]  = brne(v - bf(hi));
    }
    {
        const float v = W1[k * HDIM + (nt * 16 + c)];      // W1 orientation
        const unsigned short hi = bhi(v);
        ws[32768 + t]  = hi;
        ws[49152 + t]  = brne(v - bf(hi));
    }
}

// ---------------- v7 main: MFMA stages B/C, split-precision hi/lo ----------------
// A-matrix (LDS): 32 rows = 16 samples x (h row 2s, dh row 2s+1), bf16 hi+lo arrays.
// Stage B: [32x128] x W1^T -> z1/dz1 pairs land in-lane (D row=(l>>4)*4+reg pairs).
// u1 hi/lo overwrite dh rows; stage C: u1[16x128] x W1 -> t. hvv1 = a0 . t (a0 hi/lo
// in LDS from stage A). 3 barriers. 72 MFMA/wave; LDS 29.6KB -> 5 blocks/CU.
__global__ __launch_bounds__(NT, 2)
void dyn_mfma(const float* __restrict__ X, const float* __restrict__ Km,
              const float* __restrict__ Dm, const float* __restrict__ W0,
              const float* __restrict__ b0, const float* __restrict__ b1,
              const float* __restrict__ W2, const unsigned short* __restrict__ FR,
              float* __restrict__ out)
{
    __shared__ __align__(16) unsigned short act_hi[32 * ASTR];  // 8704 B
    __shared__ __align__(16) unsigned short act_lo[32 * ASTR];  // 8704 B
    __shared__ __align__(16) unsigned short a0_hi[16 * ASTR];   // 4352 B
    __shared__ __align__(16) unsigned short a0_lo[16 * ASTR];   // 4352 B
    __shared__ float xt[S * 16];                                // 1 KB
    __shared__ float gsm[4][16][8];                             // 2 KB
    __shared__ float hvb[2][16];
    __shared__ float hvc[4][16];

    const int tid = threadIdx.x;
    const long base = (long)blockIdx.x * S;

    // ---------------- stage A: h0/dh0/a0 -> bf16 hi+lo LDS -----------------------
    {
        const int s = tid >> 4, p = tid & 15;   // 16 threads/sample, 8 units each
        // xt staged by the same 16-thread group that reads it (same wave, DS in order)
        if (p < 4) ((float4*)xt)[s * 4 + p] = ((const float4*)(X + base * 16))[s * 4 + p];
        float xr[16];
        #pragma unroll
        for (int q = 0; q < 4; ++q) ((float4*)xr)[q] = ((const float4*)&xt[s * 16])[q];
        const float4 b0a = ((const float4*)b0)[p * 2];
        const float4 b0b = ((const float4*)b0)[p * 2 + 1];
        const float bv[8] = {b0a.x, b0a.y, b0a.z, b0a.w, b0b.x, b0b.y, b0b.z, b0b.w};
        u16x8 hh, hl, dh_, dl, ah_, al_;
        #pragma unroll
        for (int i = 0; i < 8; ++i) {
            const int k = p * 8 + i;
            const float4 wa = ((const float4*)W0)[k * 2];
            const float4 wb = ((const float4*)W0)[k * 2 + 1];
            float z = bv[i];
            z = fmaf(wa.x, xr[0], z); z = fmaf(wa.y, xr[1], z);
            z = fmaf(wa.z, xr[2], z); z = fmaf(wa.w, xr[3], z);
            z = fmaf(wb.x, xr[4], z); z = fmaf(wb.y, xr[5], z);
            z = fmaf(wb.z, xr[6], z); z = fmaf(wb.w, xr[7], z);
            float dz = wa.x * xr[8];
            dz = fmaf(wa.y, xr[9],  dz); dz = fmaf(wa.z, xr[10], dz); dz = fmaf(wa.w, xr[11], dz);
            dz = fmaf(wb.x, xr[12], dz); dz = fmaf(wb.y, xr[13], dz);
            dz = fmaf(wb.z, xr[14], dz); dz = fmaf(wb.w, xr[15], dz);
            const float h  = tanh_fast(z);
            const float e  = fmaf(-h, h, 1.0f);
            const float dh = e * dz;
            const float a0 = -2.f * h * e * dz * dz;
            hh[i]  = bhi(h);  hl[i] = brne(h  - bf(hh[i]));
            dh_[i] = bhi(dh); dl[i] = brne(dh - bf(dh_[i]));
            ah_[i] = bhi(a0); al_[i] = brne(a0 - bf(ah_[i]));
        }
        *(u16x8*)&act_hi[(2 * s)     * ASTR + p * 8] = hh;
        *(u16x8*)&act_lo[(2 * s)     * ASTR + p * 8] = hl;
        *(u16x8*)&act_hi[(2 * s + 1) * ASTR + p * 8] = dh_;
        *(u16x8*)&act_lo[(2 * s + 1) * ASTR + p * 8] = dl;
        *(u16x8*)&a0_hi[s * ASTR + p * 8] = ah_;
        *(u16x8*)&a0_lo[s * ASTR + p * 8] = al_;
    }
    __syncthreads();   // barrier 1: act/a0 complete

    const int wv = tid >> 6, l = tid & 63;
    const int m = l >> 4, c = l & 15;
    const int mt = wv >> 1, nh = wv & 1;   // stage B: m-tile (8 samples) x n-half

    // ---------------- stage B: [z1|dz1] = act x W1^T (3-pass hi/lo MFMA) ---------
    f32x4 accB[4];
    #pragma unroll
    for (int n = 0; n < 4; ++n) accB[n] = (f32x4){0.f, 0.f, 0.f, 0.f};
    #pragma unroll
    for (int ks = 0; ks < 4; ++ks) {
        const int arow = mt * 16 + c;
        const bf16x8 ah = *(const bf16x8*)&act_hi[arow * ASTR + ks * 32 + m * 8];
        const bf16x8 al = *(const bf16x8*)&act_lo[arow * ASTR + ks * 32 + m * 8];
        #pragma unroll
        for (int n = 0; n < 4; ++n) {
            const int gi = (((nh * 4 + n) * 4 + ks) * 64 + l) * 8;
            const bf16x8 bh = *(const bf16x8*)&FR[gi];
            const bf16x8 bl = *(const bf16x8*)&FR[16384 + gi];
            accB[n] = __builtin_amdgcn_mfma_f32_16x16x32_bf16(ah, bh, accB[n], 0, 0, 0);
            accB[n] = __builtin_amdgcn_mfma_f32_16x16x32_bf16(al, bh, accB[n], 0, 0, 0);
            accB[n] = __builtin_amdgcn_mfma_f32_16x16x32_bf16(ah, bl, accB[n], 0, 0, 0);
        }
    }

    // ---- stage B epilogue: lane holds (z,dz) pairs of samples sA,sB in regs -----
    {
        const int sA = mt * 8 + 2 * m, sB = sA + 1;
        float hvA = 0.f, hvB = 0.f;
        #pragma unroll
        for (int n = 0; n < 4; ++n) {
            const int j = (nh * 4 + n) * 16 + c;
            const float b1j = b1[j], w2j = W2[j];
            const float zA = accB[n][0] + b1j, dzA = accB[n][1];
            const float zB = accB[n][2] + b1j, dzB = accB[n][3];
            const float h1A = tanh_fast(zA), e1A = fmaf(-h1A, h1A, 1.f);
            const float u1A = w2j * e1A;
            hvA = fmaf(-2.f * w2j * h1A * e1A, dzA * dzA, hvA);
            const float h1B = tanh_fast(zB), e1B = fmaf(-h1B, h1B, 1.f);
            const float u1B = w2j * e1B;
            hvB = fmaf(-2.f * w2j * h1B * e1B, dzB * dzB, hvB);
            unsigned short uh = bhi(u1A);
            act_hi[(2 * sA + 1) * ASTR + j] = uh;               // u1 overwrites dh rows
            act_lo[(2 * sA + 1) * ASTR + j] = brne(u1A - bf(uh));
            uh = bhi(u1B);
            act_hi[(2 * sB + 1) * ASTR + j] = uh;
            act_lo[(2 * sB + 1) * ASTR + j] = brne(u1B - bf(uh));
        }
        #pragma unroll
        for (int mk = 1; mk <= 8; mk <<= 1) {
            hvA += __shfl_xor(hvA, mk);
            hvB += __shfl_xor(hvB, mk);
        }
        if (c == 0) { hvb[nh][sA] = hvA; hvb[nh][sB] = hvB; }
    }
    __syncthreads();   // barrier 2: u1 complete

    // ---------------- stage C: t = u1 x W1 (3-pass hi/lo MFMA, nt-quarter/wave) --
    f32x4 accC[2];
    accC[0] = (f32x4){0.f, 0.f, 0.f, 0.f};
    accC[1] = (f32x4){0.f, 0.f, 0.f, 0.f};
    #pragma unroll
    for (int ks = 0; ks < 4; ++ks) {
        const int urow = 2 * c + 1;                             // u1 row of sample c
        const bf16x8 uh = *(const bf16x8*)&act_hi[urow * ASTR + ks * 32 + m * 8];
        const bf16x8 ul = *(const bf16x8*)&act_lo[urow * ASTR + ks * 32 + m * 8];
        #pragma unroll
        for (int n2 = 0; n2 < 2; ++n2) {
            const int gi = (((wv * 2 + n2) * 4 + ks) * 64 + l) * 8;
            const bf16x8 bh = *(const bf16x8*)&FR[32768 + gi];
            const bf16x8 bl = *(const bf16x8*)&FR[49152 + gi];
            accC[n2] = __builtin_amdgcn_mfma_f32_16x16x32_bf16(uh, bh, accC[n2], 0, 0, 0);
            accC[n2] = __builtin_amdgcn_mfma_f32_16x16x32_bf16(ul, bh, accC[n2], 0, 0, 0);
            accC[n2] = __builtin_amdgcn_mfma_f32_16x16x32_bf16(uh, bl, accC[n2], 0, 0, 0);
        }
    }

    // ---- stage C epilogue: u0 = e0*t ; g partials ; hvv1 = a0 . t ---------------
    {
        float gp[4][8];
        float hv1[4] = {0.f, 0.f, 0.f, 0.f};
        #pragma unroll
        for (int p = 0; p < 4; ++p)
            #pragma unroll
            for (int d = 0; d < 8; ++d) gp[p][d] = 0.f;
        #pragma unroll
        for (int n2 = 0; n2 < 2; ++n2) {
            const int i = (wv * 2 + n2) * 16 + c;
            const float4 wa = ((const float4*)W0)[i * 2];
            const float4 wb = ((const float4*)W0)[i * 2 + 1];
            #pragma unroll
            for (int p = 0; p < 4; ++p) {
                const int s = 4 * m + p;                        // D row -> sample
                const float tv = accC[n2][p];
                const float h0 = bf(act_hi[(2 * s) * ASTR + i]) + bf(act_lo[(2 * s) * ASTR + i]);
                const float a0 = bf(a0_hi[s * ASTR + i]) + bf(a0_lo[s * ASTR + i]);
                const float e0 = fmaf(-h0, h0, 1.f);
                const float u0 = e0 * tv;
                hv1[p] = fmaf(a0, tv, hv1[p]);
                gp[p][0] = fmaf(wa.x, u0, gp[p][0]); gp[p][1] = fmaf(wa.y, u0, gp[p][1]);
                gp[p][2] = fmaf(wa.z, u0, gp[p][2]); gp[p][3] = fmaf(wa.w, u0, gp[p][3]);
                gp[p][4] = fmaf(wb.x, u0, gp[p][4]); gp[p][5] = fmaf(wb.y, u0, gp[p][5]);
                gp[p][6] = fmaf(wb.z, u0, gp[p][6]); gp[p][7] = fmaf(wb.w, u0, gp[p][7]);
            }
        }
        #pragma unroll
        for (int mk = 1; mk <= 8; mk <<= 1) {
            #pragma unroll
            for (int p = 0; p < 4; ++p) {
                #pragma unroll
                for (int d = 0; d < 8; ++d) gp[p][d] += __shfl_xor(gp[p][d], mk);
                hv1[p] += __shfl_xor(hv1[p], mk);
            }
        }
        if (c < 8) {
            #pragma unroll
            for (int p = 0; p < 4; ++p) gsm[wv][4 * m + p][c] = gp[p][c];
        } else if (c == 8) {
            #pragma unroll
            for (int p = 0; p < 4; ++p) hvc[wv][4 * m + p] = hv1[p];
        }
    }
    __syncthreads();   // barrier 3: g/hvv complete

    // ---------------- tail: force, alpha, output (threads 0..127) ----------------
    if (tid < 128) {
        const int s = tid >> 3, d = tid & 7;
        const float g = gsm[0][s][d] + gsm[1][s][d] + gsm[2][s][d] + gsm[3][s][d];
        const float hvv = hvb[0][s] + hvb[1][s]
                        + hvc[0][s] + hvc[1][s] + hvc[2][s] + hvc[3][s];
        const float4 ka = ((const float4*)Km)[d * 2], kb = ((const float4*)Km)[d * 2 + 1];
        const float4 da = ((const float4*)Dm)[d * 2], db = ((const float4*)Dm)[d * 2 + 1];
        const float* xv = &xt[s * 16];
        float f = ka.x * xv[0];
        f = fmaf(ka.y, xv[1], f);  f = fmaf(ka.z, xv[2], f);  f = fmaf(ka.w, xv[3], f);
        f = fmaf(kb.x, xv[4], f);  f = fmaf(kb.y, xv[5], f);  f = fmaf(kb.z, xv[6], f);
        f = fmaf(kb.w, xv[7], f);
        f = fmaf(da.x, xv[8], f);  f = fmaf(da.y, xv[9], f);  f = fmaf(da.z, xv[10], f);
        f = fmaf(da.w, xv[11], f); f = fmaf(db.x, xv[12], f); f = fmaf(db.y, xv[13], f);
        f = fmaf(db.z, xv[14], f); f = fmaf(db.w, xv[15], f);
        f = -f;
        float pgf = g * f, pgg = g * g;
        #pragma unroll
        for (int mk = 1; mk <= 4; mk <<= 1) {
            pgf += __shfl_xor(pgf, mk);
            pgg += __shfl_xor(pgg, mk);
        }
        const float al = (pgf + hvv) * __builtin_amdgcn_rcpf(1.f + pgg);
        out[base * 8 + tid] = fmaf(-g, al, f);
    }
}

// ---------------- correct (slow) fallback if workspace too small -----------------
__global__ void dyn_naive(const float* __restrict__ X, const float* __restrict__ Km,
                          const float* __restrict__ Dm, const float* __restrict__ W0,
                          const float* __restrict__ b0, const float* __restrict__ W1,
                          const float* __restrict__ b1, const float* __restrict__ W2,
                          float* __restrict__ out)
{
    const long sidx = (long)blockIdx.x * 64 + threadIdx.x;
    const float* xv = X + sidx * 16;
    float h0[HDIM], dh0[HDIM], a0[HDIM], u1[HDIM];
    for (int k = 0; k < HDIM; ++k) {
        float z = b0[k], dz = 0.f;
        for (int d = 0; d < 8; ++d) { z = fmaf(W0[k*8+d], xv[d], z); dz = fmaf(W0[k*8+d], xv[8+d], dz); }
        const float h = tanhf(z), e = 1.f - h*h;
        h0[k] = h; dh0[k] = e*dz; a0[k] = -2.f*h*e*dz*dz;
    }
    float hvv = 0.f;
    for (int j = 0; j < HDIM; ++j) {
        float z = b1[j], dz = 0.f, cc = 0.f;
        for (int k = 0; k < HDIM; ++k) {
            const float w = W1[j*HDIM+k];
            z = fmaf(w, h0[k], z); dz = fmaf(w, dh0[k], dz); cc = fmaf(w, a0[k], cc);
        }
        const float h = tanhf(z), e = 1.f - h*h;
        u1[j] = W2[j]*e;
        hvv += W2[j]*(e*cc - 2.f*h*e*dz*dz);
    }
    float g[8] = {0,0,0,0,0,0,0,0};
    for (int k = 0; k < HDIM; ++k) {
        float t = 0.f;
        for (int j = 0; j < HDIM; ++j) t = fmaf(u1[j], W1[j*HDIM+k], t);
        const float u0 = (1.f - h0[k]*h0[k]) * t;
        for (int d = 0; d < 8; ++d) g[d] = fmaf(W0[k*8+d], u0, g[d]);
    }
    float fd[8], gf = 0.f, gg = 0.f;
    for (int d = 0; d < 8; ++d) {
        float a = 0.f;
        for (int k = 0; k < 8; ++k) { a = fmaf(Km[d*8+k], xv[k], a); a = fmaf(Dm[d*8+k], xv[8+k], a); }
        fd[d] = -a; gf = fmaf(g[d], fd[d], gf); gg = fmaf(g[d], g[d], gg);
    }
    const float al = (gf + hvv) / (1.f + gg);
    for (int d = 0; d < 8; ++d) out[sidx*8 + d] = fd[d] - g[d]*al;
}

extern "C" void kernel_launch(void* const* d_in, const int* in_sizes, int n_in,
                              void* d_out, int out_size, void* d_ws, size_t ws_size,
                              hipStream_t stream) {
    const float* X  = (const float*)d_in[0];
    const float* Km = (const float*)d_in[1];
    const float* Dm = (const float*)d_in[2];
    const float* W0 = (const float*)d_in[3];
    const float* b0 = (const float*)d_in[4];
    const float* W1 = (const float*)d_in[5];
    const float* b1 = (const float*)d_in[6];
    const float* W2 = (const float*)d_in[7];
    // d_in[8] = b2 (unused: cancels in grad/hessian/force)
    float* out = (float*)d_out;

    const int BATCH = in_sizes[0] / 16;        // 65536
    if (ws_size >= (size_t)(4 * 16384 * sizeof(unsigned short))) {   // 128 KiB
        unsigned short* FR = (unsigned short*)d_ws;
        prep_frags<<<64, 256, 0, stream>>>(W1, FR);
        dyn_mfma<<<BATCH / S, NT, 0, stream>>>(X, Km, Dm, W0, b0, b1, W2, FR, out);
    } else {
        dyn_naive<<<BATCH / 64, 64, 0, stream>>>(X, Km, Dm, W0, b0, W1, b1, W2, out);
    }
}

// Round 7
// 133.605 us; speedup vs baseline: 3.5553x; 1.0622x over previous
//
#include <hip/hip_runtime.h>
#include <math.h>

#define HDIM 128
#define S 16            // samples per workgroup
#define NT 256
#define ASTR 136        // bf16 row stride (ushort) for act arrays
#define PSTR 132        // u32 row stride for packed a0/u0

typedef __attribute__((ext_vector_type(8))) short  bf16x8;   // MFMA A/B frag
typedef __attribute__((ext_vector_type(8))) unsigned short u16x8;
typedef __attribute__((ext_vector_type(4))) float  f32x4;    // MFMA C/D frag

// tanh(x) = 1 - 2/(exp(2x)+1): NaN-free for any x, abs err ~1e-7.
__device__ __forceinline__ float tanh_fast(float x){
    const float e = __expf(2.0f * x);
    return 1.0f - 2.0f * __builtin_amdgcn_rcpf(e + 1.0f);
}
// bf16 split helpers: v ~= hi + lo, |err| <~ 2^-18 |v|
__device__ __forceinline__ unsigned short bhi(float v){
    return (unsigned short)(__float_as_uint(v) >> 16);
}
__device__ __forceinline__ unsigned short brne(float v){
    unsigned u = __float_as_uint(v);
    return (unsigned short)((u + 0x7FFFu + ((u >> 16) & 1u)) >> 16);
}
__device__ __forceinline__ float bf(unsigned short u){
    return __uint_as_float(((unsigned)u) << 16);
}
__device__ __forceinline__ unsigned pack_hl(float v){
    const unsigned short hi = bhi(v);
    const unsigned short lo = brne(v - bf(hi));
    return (((unsigned)hi) << 16) | (unsigned)lo;
}

// ---------------- prep: pack W1 (B/C orientations) + W0 into B-frag hi/lo --------
// ws layout (ushort): [0]=BhB [16384]=BlB [32768]=BhC [49152]=BlC
//                     [65536]=W0h(2048) [67584]=W0l(2048)   -> 139,264 B total
__global__ void prep_frags(const float* __restrict__ W1, const float* __restrict__ W0,
                           unsigned short* __restrict__ ws){
    const int t = blockIdx.x * 256 + threadIdx.x;
    if (t < 16384) {
        const int r = t & 7, l = (t >> 3) & 63, tile = t >> 9;
        const int nt = tile >> 2, ks = tile & 3;
        const int m = l >> 4, c = l & 15;
        const int k = ks * 32 + m * 8 + r;
        {
            const float v = W1[(nt * 16 + c) * HDIM + k];      // W1^T orientation (stage B)
            const unsigned short hi = bhi(v);
            ws[t]         = hi;
            ws[16384 + t] = brne(v - bf(hi));
        }
        {
            const float v = W1[k * HDIM + (nt * 16 + c)];      // W1 orientation (stage C)
            const unsigned short hi = bhi(v);
            ws[32768 + t] = hi;
            ws[49152 + t] = brne(v - bf(hi));
        }
    } else if (t < 18432) {
        const int t2 = t - 16384;                              // W0 B-frag (stage D)
        const int r = t2 & 7, l = (t2 >> 3) & 63, ks = t2 >> 9;
        const int m = l >> 4, c = l & 15;
        const int k = ks * 32 + m * 8 + r;
        const float v = (c < 8) ? W0[k * 8 + c] : 0.f;         // cols 8..15 zero
        const unsigned short hi = bhi(v);
        ws[65536 + t2] = hi;
        ws[67584 + t2] = brne(v - bf(hi));
    }
}

// ---------------- v8 main: MFMA stages B/C/D, split-precision hi/lo --------------
// v7 + stage D: g = u0 x W0 on the matrix pipe (wave 0 only, 12 MFMA) replacing the
// 144-shfl butterfly. a0 stored packed (hi|lo u32); u0 overwrites it in place.
__global__ __launch_bounds__(NT, 2)
void dyn_mfma(const float* __restrict__ X, const float* __restrict__ Km,
              const float* __restrict__ Dm, const float* __restrict__ W0,
              const float* __restrict__ b0, const float* __restrict__ b1,
              const float* __restrict__ W2, const unsigned short* __restrict__ FR,
              float* __restrict__ out)
{
    __shared__ __align__(16) unsigned short act_hi[32 * ASTR];  // 8704 B
    __shared__ __align__(16) unsigned short act_lo[32 * ASTR];  // 8704 B
    __shared__ __align__(16) unsigned int   a0pk[16 * PSTR];    // 8448 B (-> u0pk)
    __shared__ float xt[S * 16];                                // 1 KB
    __shared__ float hvb[2][16];
    __shared__ float hvc[4][16];

    const int tid = threadIdx.x;
    const long base = (long)blockIdx.x * S;

    // ---------------- stage A: h0/dh0 -> bf16 hi+lo LDS; a0 packed ---------------
    {
        const int s = tid >> 4, p = tid & 15;   // 16 threads/sample, 8 units each
        if (p < 4) ((float4*)xt)[s * 4 + p] = ((const float4*)(X + base * 16))[s * 4 + p];
        float xr[16];
        #pragma unroll
        for (int q = 0; q < 4; ++q) ((float4*)xr)[q] = ((const float4*)&xt[s * 16])[q];
        const float4 b0a = ((const float4*)b0)[p * 2];
        const float4 b0b = ((const float4*)b0)[p * 2 + 1];
        const float bv[8] = {b0a.x, b0a.y, b0a.z, b0a.w, b0b.x, b0b.y, b0b.z, b0b.w};
        u16x8 hh, hl, dh_, dl;
        unsigned apk[8];
        #pragma unroll
        for (int i = 0; i < 8; ++i) {
            const int k = p * 8 + i;
            const float4 wa = ((const float4*)W0)[k * 2];
            const float4 wb = ((const float4*)W0)[k * 2 + 1];
            float z = bv[i];
            z = fmaf(wa.x, xr[0], z); z = fmaf(wa.y, xr[1], z);
            z = fmaf(wa.z, xr[2], z); z = fmaf(wa.w, xr[3], z);
            z = fmaf(wb.x, xr[4], z); z = fmaf(wb.y, xr[5], z);
            z = fmaf(wb.z, xr[6], z); z = fmaf(wb.w, xr[7], z);
            float dz = wa.x * xr[8];
            dz = fmaf(wa.y, xr[9],  dz); dz = fmaf(wa.z, xr[10], dz); dz = fmaf(wa.w, xr[11], dz);
            dz = fmaf(wb.x, xr[12], dz); dz = fmaf(wb.y, xr[13], dz);
            dz = fmaf(wb.z, xr[14], dz); dz = fmaf(wb.w, xr[15], dz);
            const float h  = tanh_fast(z);
            const float e  = fmaf(-h, h, 1.0f);
            const float dh = e * dz;
            const float a0 = -2.f * h * e * dz * dz;
            hh[i]  = bhi(h);  hl[i] = brne(h  - bf(hh[i]));
            dh_[i] = bhi(dh); dl[i] = brne(dh - bf(dh_[i]));
            apk[i] = pack_hl(a0);
        }
        *(u16x8*)&act_hi[(2 * s)     * ASTR + p * 8] = hh;
        *(u16x8*)&act_lo[(2 * s)     * ASTR + p * 8] = hl;
        *(u16x8*)&act_hi[(2 * s + 1) * ASTR + p * 8] = dh_;
        *(u16x8*)&act_lo[(2 * s + 1) * ASTR + p * 8] = dl;
        *(uint4*)&a0pk[s * PSTR + p * 8]     = *(uint4*)&apk[0];
        *(uint4*)&a0pk[s * PSTR + p * 8 + 4] = *(uint4*)&apk[4];
    }
    __syncthreads();   // barrier 1: act/a0 complete

    const int wv = tid >> 6, l = tid & 63;
    const int m = l >> 4, c = l & 15;
    const int mt = wv >> 1, nh = wv & 1;   // stage B: m-tile (8 samples) x n-half

    // ---------------- stage B: [z1|dz1] = act x W1^T (3-pass hi/lo MFMA) ---------
    f32x4 accB[4];
    #pragma unroll
    for (int n = 0; n < 4; ++n) accB[n] = (f32x4){0.f, 0.f, 0.f, 0.f};
    #pragma unroll
    for (int ks = 0; ks < 4; ++ks) {
        const int arow = mt * 16 + c;
        const bf16x8 ah = *(const bf16x8*)&act_hi[arow * ASTR + ks * 32 + m * 8];
        const bf16x8 al = *(const bf16x8*)&act_lo[arow * ASTR + ks * 32 + m * 8];
        #pragma unroll
        for (int n = 0; n < 4; ++n) {
            const int gi = (((nh * 4 + n) * 4 + ks) * 64 + l) * 8;
            const bf16x8 bh = *(const bf16x8*)&FR[gi];
            const bf16x8 bl = *(const bf16x8*)&FR[16384 + gi];
            accB[n] = __builtin_amdgcn_mfma_f32_16x16x32_bf16(ah, bh, accB[n], 0, 0, 0);
            accB[n] = __builtin_amdgcn_mfma_f32_16x16x32_bf16(al, bh, accB[n], 0, 0, 0);
            accB[n] = __builtin_amdgcn_mfma_f32_16x16x32_bf16(ah, bl, accB[n], 0, 0, 0);
        }
    }

    // ---- stage B epilogue: lane holds (z,dz) pairs of samples sA,sB in regs -----
    {
        const int sA = mt * 8 + 2 * m, sB = sA + 1;
        float hvA = 0.f, hvB = 0.f;
        #pragma unroll
        for (int n = 0; n < 4; ++n) {
            const int j = (nh * 4 + n) * 16 + c;
            const float b1j = b1[j], w2j = W2[j];
            const float zA = accB[n][0] + b1j, dzA = accB[n][1];
            const float zB = accB[n][2] + b1j, dzB = accB[n][3];
            const float h1A = tanh_fast(zA), e1A = fmaf(-h1A, h1A, 1.f);
            const float u1A = w2j * e1A;
            hvA = fmaf(-2.f * w2j * h1A * e1A, dzA * dzA, hvA);
            const float h1B = tanh_fast(zB), e1B = fmaf(-h1B, h1B, 1.f);
            const float u1B = w2j * e1B;
            hvB = fmaf(-2.f * w2j * h1B * e1B, dzB * dzB, hvB);
            unsigned short uh = bhi(u1A);
            act_hi[(2 * sA + 1) * ASTR + j] = uh;               // u1 overwrites dh rows
            act_lo[(2 * sA + 1) * ASTR + j] = brne(u1A - bf(uh));
            uh = bhi(u1B);
            act_hi[(2 * sB + 1) * ASTR + j] = uh;
            act_lo[(2 * sB + 1) * ASTR + j] = brne(u1B - bf(uh));
        }
        #pragma unroll
        for (int mk = 1; mk <= 8; mk <<= 1) {
            hvA += __shfl_xor(hvA, mk);
            hvB += __shfl_xor(hvB, mk);
        }
        if (c == 0) { hvb[nh][sA] = hvA; hvb[nh][sB] = hvB; }
    }
    __syncthreads();   // barrier 2: u1 complete

    // ---------------- stage C: t = u1 x W1 (3-pass hi/lo MFMA, i-quarter/wave) ---
    f32x4 accC[2];
    accC[0] = (f32x4){0.f, 0.f, 0.f, 0.f};
    accC[1] = (f32x4){0.f, 0.f, 0.f, 0.f};
    #pragma unroll
    for (int ks = 0; ks < 4; ++ks) {
        const int urow = 2 * c + 1;                             // u1 row of sample c
        const bf16x8 uh = *(const bf16x8*)&act_hi[urow * ASTR + ks * 32 + m * 8];
        const bf16x8 ul = *(const bf16x8*)&act_lo[urow * ASTR + ks * 32 + m * 8];
        #pragma unroll
        for (int n2 = 0; n2 < 2; ++n2) {
            const int gi = (((wv * 2 + n2) * 4 + ks) * 64 + l) * 8;
            const bf16x8 bh = *(const bf16x8*)&FR[32768 + gi];
            const bf16x8 bl = *(const bf16x8*)&FR[49152 + gi];
            accC[n2] = __builtin_amdgcn_mfma_f32_16x16x32_bf16(uh, bh, accC[n2], 0, 0, 0);
            accC[n2] = __builtin_amdgcn_mfma_f32_16x16x32_bf16(ul, bh, accC[n2], 0, 0, 0);
            accC[n2] = __builtin_amdgcn_mfma_f32_16x16x32_bf16(uh, bl, accC[n2], 0, 0, 0);
        }
    }

    // ---- stage C epilogue: hvv1 += a0.t ; u0 = e0*t packed, overwrites a0pk -----
    {
        float hv1[4] = {0.f, 0.f, 0.f, 0.f};
        #pragma unroll
        for (int n2 = 0; n2 < 2; ++n2) {
            const int i = (wv * 2 + n2) * 16 + c;
            #pragma unroll
            for (int p = 0; p < 4; ++p) {
                const int s = 4 * m + p;                        // D row -> sample
                const float tv = accC[n2][p];
                const float h0 = bf(act_hi[(2 * s) * ASTR + i]) + bf(act_lo[(2 * s) * ASTR + i]);
                const unsigned apk = a0pk[s * PSTR + i];
                const float a0 = __uint_as_float(apk & 0xFFFF0000u)
                               + __uint_as_float(apk << 16);
                const float e0 = fmaf(-h0, h0, 1.f);
                const float u0 = e0 * tv;
                hv1[p] = fmaf(a0, tv, hv1[p]);
                a0pk[s * PSTR + i] = pack_hl(u0);               // same-lane RMW, no race
            }
        }
        #pragma unroll
        for (int mk = 1; mk <= 8; mk <<= 1) {
            #pragma unroll
            for (int p = 0; p < 4; ++p) hv1[p] += __shfl_xor(hv1[p], mk);
        }
        if (c == 0) {
            #pragma unroll
            for (int p = 0; p < 4; ++p) hvc[wv][4 * m + p] = hv1[p];
        }
    }
    __syncthreads();   // barrier 3 (last): u0/hv complete

    if (wv != 0) return;   // waves 1-3 done; wave 0 finishes the block

    // ---------------- stage D (wave 0): g = u0 x W0 (3-pass hi/lo MFMA) ----------
    f32x4 accG = (f32x4){0.f, 0.f, 0.f, 0.f};
    #pragma unroll
    for (int ks = 0; ks < 4; ++ks) {
        unsigned u[8];
        *(uint4*)&u[0] = *(const uint4*)&a0pk[c * PSTR + ks * 32 + m * 8];
        *(uint4*)&u[4] = *(const uint4*)&a0pk[c * PSTR + ks * 32 + m * 8 + 4];
        bf16x8 ah, al;
        #pragma unroll
        for (int j = 0; j < 8; ++j) {
            ah[j] = (short)(u[j] >> 16);
            al[j] = (short)(u[j] & 0xFFFFu);
        }
        const int gi = (ks * 64 + l) * 8;
        const bf16x8 bh = *(const bf16x8*)&FR[65536 + gi];
        const bf16x8 bl = *(const bf16x8*)&FR[67584 + gi];
        accG = __builtin_amdgcn_mfma_f32_16x16x32_bf16(ah, bh, accG, 0, 0, 0);
        accG = __builtin_amdgcn_mfma_f32_16x16x32_bf16(al, bh, accG, 0, 0, 0);
        accG = __builtin_amdgcn_mfma_f32_16x16x32_bf16(ah, bl, accG, 0, 0, 0);
    }

    // ---------------- tail (wave 0): force, alpha, output ------------------------
    {
        const int dd = c & 7;
        const float4 ka = ((const float4*)Km)[dd * 2], kb = ((const float4*)Km)[dd * 2 + 1];
        const float4 da = ((const float4*)Dm)[dd * 2], db = ((const float4*)Dm)[dd * 2 + 1];
        #pragma unroll
        for (int p = 0; p < 4; ++p) {
            const int s = 4 * m + p;
            const float g = accG[p];                            // g[s][c] (c<8; else 0)
            const float hvv = hvb[0][s] + hvb[1][s]
                            + hvc[0][s] + hvc[1][s] + hvc[2][s] + hvc[3][s];
            const float* xv = &xt[s * 16];
            float f = ka.x * xv[0];
            f = fmaf(ka.y, xv[1], f);  f = fmaf(ka.z, xv[2], f);  f = fmaf(ka.w, xv[3], f);
            f = fmaf(kb.x, xv[4], f);  f = fmaf(kb.y, xv[5], f);  f = fmaf(kb.z, xv[6], f);
            f = fmaf(kb.w, xv[7], f);
            f = fmaf(da.x, xv[8], f);  f = fmaf(da.y, xv[9], f);  f = fmaf(da.z, xv[10], f);
            f = fmaf(da.w, xv[11], f); f = fmaf(db.x, xv[12], f); f = fmaf(db.y, xv[13], f);
            f = fmaf(db.z, xv[14], f); f = fmaf(db.w, xv[15], f);
            f = -f;
            float pgf = g * f, pgg = g * g;                     // c>=8 lanes contribute 0
            #pragma unroll
            for (int mk = 1; mk <= 8; mk <<= 1) {
                pgf += __shfl_xor(pgf, mk);
                pgg += __shfl_xor(pgg, mk);
            }
            const float al_ = (pgf + hvv) * __builtin_amdgcn_rcpf(1.f + pgg);
            if (c < 8)
                out[(base + s) * 8 + c] = fmaf(-g, al_, f);
        }
    }
}

// ---------------- correct (slow) fallback if workspace too small -----------------
__global__ void dyn_naive(const float* __restrict__ X, const float* __restrict__ Km,
                          const float* __restrict__ Dm, const float* __restrict__ W0,
                          const float* __restrict__ b0, const float* __restrict__ W1,
                          const float* __restrict__ b1, const float* __restrict__ W2,
                          float* __restrict__ out)
{
    const long sidx = (long)blockIdx.x * 64 + threadIdx.x;
    const float* xv = X + sidx * 16;
    float h0[HDIM], dh0[HDIM], a0[HDIM], u1[HDIM];
    for (int k = 0; k < HDIM; ++k) {
        float z = b0[k], dz = 0.f;
        for (int d = 0; d < 8; ++d) { z = fmaf(W0[k*8+d], xv[d], z); dz = fmaf(W0[k*8+d], xv[8+d], dz); }
        const float h = tanhf(z), e = 1.f - h*h;
        h0[k] = h; dh0[k] = e*dz; a0[k] = -2.f*h*e*dz*dz;
    }
    float hvv = 0.f;
    for (int j = 0; j < HDIM; ++j) {
        float z = b1[j], dz = 0.f, cc = 0.f;
        for (int k = 0; k < HDIM; ++k) {
            const float w = W1[j*HDIM+k];
            z = fmaf(w, h0[k], z); dz = fmaf(w, dh0[k], dz); cc = fmaf(w, a0[k], cc);
        }
        const float h = tanhf(z), e = 1.f - h*h;
        u1[j] = W2[j]*e;
        hvv += W2[j]*(e*cc - 2.f*h*e*dz*dz);
    }
    float g[8] = {0,0,0,0,0,0,0,0};
    for (int k = 0; k < HDIM; ++k) {
        float t = 0.f;
        for (int j = 0; j < HDIM; ++j) t = fmaf(u1[j], W1[j*HDIM+k], t);
        const float u0 = (1.f - h0[k]*h0[k]) * t;
        for (int d = 0; d < 8; ++d) g[d] = fmaf(W0[k*8+d], u0, g[d]);
    }
    float fd[8], gf = 0.f, gg = 0.f;
    for (int d = 0; d < 8; ++d) {
        float a = 0.f;
        for (int k = 0; k < 8; ++k) { a = fmaf(Km[d*8+k], xv[k], a); a = fmaf(Dm[d*8+k], xv[8+k], a); }
        fd[d] = -a; gf = fmaf(g[d], fd[d], gf); gg = fmaf(g[d], g[d], gg);
    }
    const float al = (gf + hvv) / (1.f + gg);
    for (int d = 0; d < 8; ++d) out[sidx*8 + d] = fd[d] - g[d]*al;
}

extern "C" void kernel_launch(void* const* d_in, const int* in_sizes, int n_in,
                              void* d_out, int out_size, void* d_ws, size_t ws_size,
                              hipStream_t stream) {
    const float* X  = (const float*)d_in[0];
    const float* Km = (const float*)d_in[1];
    const float* Dm = (const float*)d_in[2];
    const float* W0 = (const float*)d_in[3];
    const float* b0 = (const float*)d_in[4];
    const float* W1 = (const float*)d_in[5];
    const float* b1 = (const float*)d_in[6];
    const float* W2 = (const float*)d_in[7];
    // d_in[8] = b2 (unused: cancels in grad/hessian/force)
    float* out = (float*)d_out;

    const int BATCH = in_sizes[0] / 16;        // 65536
    if (ws_size >= (size_t)(69632 * sizeof(unsigned short))) {   // 136 KiB
        unsigned short* FR = (unsigned short*)d_ws;
        prep_frags<<<72, 256, 0, stream>>>(W1, W0, FR);
        dyn_mfma<<<BATCH / S, NT, 0, stream>>>(X, Km, Dm, W0, b0, b1, W2, FR, out);
    } else {
        dyn_naive<<<BATCH / 64, 64, 0, stream>>>(X, Km, Dm, W0, b0, W1, b1, W2, out);
    }
}

// Round 9
// 131.168 us; speedup vs baseline: 3.6213x; 1.0186x over previous
//
#include <hip/hip_runtime.h>
#include <math.h>

#define HDIM 128
#define S 16            // samples per workgroup
#define NT 256
#define ASTR 136        // bf16 row stride (ushort)
#define PSTR 132        // u32 row stride

typedef __attribute__((ext_vector_type(8))) short  bf16x8;   // MFMA A/B frag
typedef __attribute__((ext_vector_type(8))) unsigned short u16x8;
typedef __attribute__((ext_vector_type(4))) float  f32x4;    // MFMA C/D frag

// tanh(x) = 1 - 2/(exp(2x)+1): NaN-free for any x, abs err ~1e-7.
__device__ __forceinline__ float tanh_fast(float x){
    const float e = __expf(2.0f * x);
    return 1.0f - 2.0f * __builtin_amdgcn_rcpf(e + 1.0f);
}
// bf16 split helpers: v ~= hi + lo
__device__ __forceinline__ unsigned short bhi(float v){
    return (unsigned short)(__float_as_uint(v) >> 16);
}
__device__ __forceinline__ unsigned short brne(float v){
    unsigned u = __float_as_uint(v);
    return (unsigned short)((u + 0x7FFFu + ((u >> 16) & 1u)) >> 16);
}
__device__ __forceinline__ float bf(unsigned short u){
    return __uint_as_float(((unsigned)u) << 16);
}
__device__ __forceinline__ unsigned pack_hl(float v){
    const unsigned short hi = bhi(v);
    const unsigned short lo = brne(v - bf(hi));
    return (((unsigned)hi) << 16) | (unsigned)lo;
}

// ---------------- prep: pack W1 (B/C orientations) + W0 into B-frag hi/lo --------
// ws layout (ushort): [0]=BhB [16384]=BlB [32768]=BhC [49152]=BlC
//                     [65536]=W0h(2048) [67584]=W0l(2048)
__global__ void prep_frags(const float* __restrict__ W1, const float* __restrict__ W0,
                           unsigned short* __restrict__ ws){
    const int t = blockIdx.x * 256 + threadIdx.x;
    if (t < 16384) {
        const int r = t & 7, l = (t >> 3) & 63, tile = t >> 9;
        const int nt = tile >> 2, ks = tile & 3;
        const int m = l >> 4, c = l & 15;
        const int k = ks * 32 + m * 8 + r;
        {
            const float v = W1[(nt * 16 + c) * HDIM + k];      // W1^T orientation (stage B)
            const unsigned short hi = bhi(v);
            ws[t]         = hi;
            ws[16384 + t] = brne(v - bf(hi));
        }
        {
            const float v = W1[k * HDIM + (nt * 16 + c)];      // W1 orientation (stage C)
            const unsigned short hi = bhi(v);
            ws[32768 + t] = hi;
            ws[49152 + t] = brne(v - bf(hi));
        }
    } else if (t < 18432) {
        const int t2 = t - 16384;                              // W0 B-frag (stage D)
        const int r = t2 & 7, l = (t2 >> 3) & 63, ks = t2 >> 9;
        const int m = l >> 4, c = l & 15;
        const int k = ks * 32 + m * 8 + r;
        const float v = (c < 8) ? W0[k * 8 + c] : 0.f;         // cols 8..15 zero
        const unsigned short hi = bhi(v);
        ws[65536 + t2] = hi;
        ws[67584 + t2] = brne(v - bf(hi));
    }
}

// ---------------- v10: v9 pipelining + u1-overwrite race FIXED -------------------
// v9 (and latently v7/v8) raced: waves 2mt and 2mt+1 both READ the dh rows of
// samples mt*8..mt*8+7 in stage B, while each wave's epilogue OVERWROTE those rows
// with u1 (different column halves) with no intervening barrier -> nondeterministic
// absmax (0.074 / 0.125 lucky passes, 0.25 / 468 in v9's schedule). Fix: compute
// the epilogue into registers, __syncthreads(), THEN store u1 (4 barriers total).
__global__ __launch_bounds__(NT)
void dyn_mfma(const float* __restrict__ X, const float* __restrict__ Km,
              const float* __restrict__ Dm, const float* __restrict__ W0,
              const float* __restrict__ b0, const float* __restrict__ b1,
              const float* __restrict__ W2, const unsigned short* __restrict__ FR,
              float* __restrict__ out)
{
    __shared__ __align__(16) unsigned short act_hi[32 * ASTR];  // 8704 B
    __shared__ __align__(16) unsigned short act_lo[32 * ASTR];  // 8704 B
    __shared__ __align__(16) unsigned int   a0pk[16 * PSTR];    // 8448 B (-> u0pk)
    __shared__ float xt[S * 16];                                // 1 KB
    __shared__ float hvb[2][16];
    __shared__ float hvc[4][16];

    const int tid = threadIdx.x;
    const long base = (long)blockIdx.x * S;

    const int wv = tid >> 6, l = tid & 63;
    const int m = l >> 4, c = l & 15;
    const int mt = wv >> 1, nh = wv & 1;   // stage B: m-tile (8 samples) x n-half

    // ---------------- stage A: h0/dh0 -> bf16 hi+lo LDS; a0 packed ---------------
    {
        const int s = tid >> 4, p = tid & 15;   // 16 threads/sample, 8 units each
        if (p < 4) ((float4*)xt)[s * 4 + p] = ((const float4*)(X + base * 16))[s * 4 + p];
        // preload all W0 rows + biases first (wide batch, one wait)
        float4 w0r[16];
        #pragma unroll
        for (int i = 0; i < 8; ++i) {
            w0r[2 * i]     = ((const float4*)W0)[(p * 8 + i) * 2];
            w0r[2 * i + 1] = ((const float4*)W0)[(p * 8 + i) * 2 + 1];
        }
        const float4 b0a = ((const float4*)b0)[p * 2];
        const float4 b0b = ((const float4*)b0)[p * 2 + 1];
        const float bv[8] = {b0a.x, b0a.y, b0a.z, b0a.w, b0b.x, b0b.y, b0b.z, b0b.w};
        float xr[16];
        #pragma unroll
        for (int q = 0; q < 4; ++q) ((float4*)xr)[q] = ((const float4*)&xt[s * 16])[q];
        u16x8 hh, hl, dh_, dl;
        unsigned apk[8];
        #pragma unroll
        for (int i = 0; i < 8; ++i) {
            const float4 wa = w0r[2 * i];
            const float4 wb = w0r[2 * i + 1];
            float z = bv[i];
            z = fmaf(wa.x, xr[0], z); z = fmaf(wa.y, xr[1], z);
            z = fmaf(wa.z, xr[2], z); z = fmaf(wa.w, xr[3], z);
            z = fmaf(wb.x, xr[4], z); z = fmaf(wb.y, xr[5], z);
            z = fmaf(wb.z, xr[6], z); z = fmaf(wb.w, xr[7], z);
            float dz = wa.x * xr[8];
            dz = fmaf(wa.y, xr[9],  dz); dz = fmaf(wa.z, xr[10], dz); dz = fmaf(wa.w, xr[11], dz);
            dz = fmaf(wb.x, xr[12], dz); dz = fmaf(wb.y, xr[13], dz);
            dz = fmaf(wb.z, xr[14], dz); dz = fmaf(wb.w, xr[15], dz);
            const float h  = tanh_fast(z);
            const float e  = fmaf(-h, h, 1.0f);
            const float dh = e * dz;
            const float a0 = -2.f * h * e * dz * dz;
            hh[i]  = bhi(h);  hl[i] = brne(h  - bf(hh[i]));
            dh_[i] = bhi(dh); dl[i] = brne(dh - bf(dh_[i]));
            apk[i] = pack_hl(a0);
        }
        *(u16x8*)&act_hi[(2 * s)     * ASTR + p * 8] = hh;
        *(u16x8*)&act_lo[(2 * s)     * ASTR + p * 8] = hl;
        *(u16x8*)&act_hi[(2 * s + 1) * ASTR + p * 8] = dh_;
        *(u16x8*)&act_lo[(2 * s + 1) * ASTR + p * 8] = dl;
        *(uint4*)&a0pk[s * PSTR + p * 8]     = *(uint4*)&apk[0];
        *(uint4*)&a0pk[s * PSTR + p * 8 + 4] = *(uint4*)&apk[4];
    }

    // issue FIRST stage-B FR tile + epilogue scalars before the barrier (FR-only deps)
    bf16x8 pbh[2][4], pbl[2][4];
    #pragma unroll
    for (int ks = 0; ks < 4; ++ks) {
        const int gi = (((nh * 4 + 0) * 4 + ks) * 64 + l) * 8;
        pbh[0][ks] = *(const bf16x8*)&FR[gi];
        pbl[0][ks] = *(const bf16x8*)&FR[16384 + gi];
    }
    float b1v[4], w2v[4];
    #pragma unroll
    for (int n = 0; n < 4; ++n) {
        const int j = (nh * 4 + n) * 16 + c;
        b1v[n] = b1[j];
        w2v[n] = W2[j];
    }
    __syncthreads();   // barrier 1: act/a0 complete

    // ---------------- stage B: [z1|dz1] = act x W1^T (3-pass hi/lo MFMA) ---------
    f32x4 accB[4];
    #pragma unroll
    for (int n = 0; n < 4; ++n) accB[n] = (f32x4){0.f, 0.f, 0.f, 0.f};
    {
        const int arow = mt * 16 + c;
        bf16x8 ah[4], al[4];
        #pragma unroll
        for (int ks = 0; ks < 4; ++ks) {
            ah[ks] = *(const bf16x8*)&act_hi[arow * ASTR + ks * 32 + m * 8];
            al[ks] = *(const bf16x8*)&act_lo[arow * ASTR + ks * 32 + m * 8];
        }
        #pragma unroll
        for (int n = 0; n < 4; ++n) {
            const int cur = n & 1;
            if (n < 3) {                       // prefetch next n-tile (8 frags in flight)
                #pragma unroll
                for (int ks = 0; ks < 4; ++ks) {
                    const int gi = (((nh * 4 + n + 1) * 4 + ks) * 64 + l) * 8;
                    pbh[cur ^ 1][ks] = *(const bf16x8*)&FR[gi];
                    pbl[cur ^ 1][ks] = *(const bf16x8*)&FR[16384 + gi];
                }
            }
            #pragma unroll
            for (int ks = 0; ks < 4; ++ks) {
                accB[n] = __builtin_amdgcn_mfma_f32_16x16x32_bf16(ah[ks], pbh[cur][ks], accB[n], 0, 0, 0);
                accB[n] = __builtin_amdgcn_mfma_f32_16x16x32_bf16(al[ks], pbh[cur][ks], accB[n], 0, 0, 0);
                accB[n] = __builtin_amdgcn_mfma_f32_16x16x32_bf16(ah[ks], pbl[cur][ks], accB[n], 0, 0, 0);
            }
        }
    }

    // ---- stage B epilogue, part 1: compute u1/hvv into REGISTERS only -----------
    const int sA = mt * 8 + 2 * m, sB = sA + 1;
    float u1Av[4], u1Bv[4];
    float hvA = 0.f, hvB = 0.f;
    #pragma unroll
    for (int n = 0; n < 4; ++n) {
        const float zA = accB[n][0] + b1v[n], dzA = accB[n][1];
        const float zB = accB[n][2] + b1v[n], dzB = accB[n][3];
        const float h1A = tanh_fast(zA), e1A = fmaf(-h1A, h1A, 1.f);
        u1Av[n] = w2v[n] * e1A;
        hvA = fmaf(-2.f * w2v[n] * h1A * e1A, dzA * dzA, hvA);
        const float h1B = tanh_fast(zB), e1B = fmaf(-h1B, h1B, 1.f);
        u1Bv[n] = w2v[n] * e1B;
        hvB = fmaf(-2.f * w2v[n] * h1B * e1B, dzB * dzB, hvB);
    }
    #pragma unroll
    for (int mk = 1; mk <= 8; mk <<= 1) {
        hvA += __shfl_xor(hvA, mk);
        hvB += __shfl_xor(hvB, mk);
    }

    // issue ALL stage-C FR frags before the barriers (FR-only deps; latency hides)
    bf16x8 cbh[2][4], cbl[2][4];
    #pragma unroll
    for (int n2 = 0; n2 < 2; ++n2)
        #pragma unroll
        for (int ks = 0; ks < 4; ++ks) {
            const int gi = (((wv * 2 + n2) * 4 + ks) * 64 + l) * 8;
            cbh[n2][ks] = *(const bf16x8*)&FR[32768 + gi];
            cbl[n2][ks] = *(const bf16x8*)&FR[49152 + gi];
        }

    __syncthreads();   // barrier 2 (RACE FIX): all waves done READING dh rows

    // ---- stage B epilogue, part 2: store u1 over the dead dh rows ---------------
    #pragma unroll
    for (int n = 0; n < 4; ++n) {
        const int j = (nh * 4 + n) * 16 + c;
        unsigned short uh = bhi(u1Av[n]);
        act_hi[(2 * sA + 1) * ASTR + j] = uh;
        act_lo[(2 * sA + 1) * ASTR + j] = brne(u1Av[n] - bf(uh));
        uh = bhi(u1Bv[n]);
        act_hi[(2 * sB + 1) * ASTR + j] = uh;
        act_lo[(2 * sB + 1) * ASTR + j] = brne(u1Bv[n] - bf(uh));
    }
    if (c == 0) { hvb[nh][sA] = hvA; hvb[nh][sB] = hvB; }
    __syncthreads();   // barrier 3: u1 complete

    // ---------------- stage C: t = u1 x W1 (3-pass hi/lo MFMA, i-quarter/wave) ---
    f32x4 accC[2];
    accC[0] = (f32x4){0.f, 0.f, 0.f, 0.f};
    accC[1] = (f32x4){0.f, 0.f, 0.f, 0.f};
    {
        const int urow = 2 * c + 1;                             // u1 row of sample c
        bf16x8 uh4[4], ul4[4];
        #pragma unroll
        for (int ks = 0; ks < 4; ++ks) {
            uh4[ks] = *(const bf16x8*)&act_hi[urow * ASTR + ks * 32 + m * 8];
            ul4[ks] = *(const bf16x8*)&act_lo[urow * ASTR + ks * 32 + m * 8];
        }
        #pragma unroll
        for (int n2 = 0; n2 < 2; ++n2)
            #pragma unroll
            for (int ks = 0; ks < 4; ++ks) {
                accC[n2] = __builtin_amdgcn_mfma_f32_16x16x32_bf16(uh4[ks], cbh[n2][ks], accC[n2], 0, 0, 0);
                accC[n2] = __builtin_amdgcn_mfma_f32_16x16x32_bf16(ul4[ks], cbh[n2][ks], accC[n2], 0, 0, 0);
                accC[n2] = __builtin_amdgcn_mfma_f32_16x16x32_bf16(uh4[ks], cbl[n2][ks], accC[n2], 0, 0, 0);
            }
    }

    // ---- stage C epilogue: hvv1 += a0.t ; u0 = e0*t packed, overwrites a0pk -----
    // (a0pk RMW is same-lane per (s,i); u1 rows untouched; h0 rows untouched)
    {
        float hv1[4] = {0.f, 0.f, 0.f, 0.f};
        #pragma unroll
        for (int n2 = 0; n2 < 2; ++n2) {
            const int i = (wv * 2 + n2) * 16 + c;
            #pragma unroll
            for (int p = 0; p < 4; ++p) {
                const int s = 4 * m + p;                        // D row -> sample
                const float tv = accC[n2][p];
                const float h0 = bf(act_hi[(2 * s) * ASTR + i]) + bf(act_lo[(2 * s) * ASTR + i]);
                const unsigned apk = a0pk[s * PSTR + i];
                const float a0 = __uint_as_float(apk & 0xFFFF0000u)
                               + __uint_as_float(apk << 16);
                const float e0 = fmaf(-h0, h0, 1.f);
                const float u0 = e0 * tv;
                hv1[p] = fmaf(a0, tv, hv1[p]);
                a0pk[s * PSTR + i] = pack_hl(u0);               // same-lane RMW, no race
            }
        }
        #pragma unroll
        for (int mk = 1; mk <= 8; mk <<= 1) {
            #pragma unroll
            for (int p = 0; p < 4; ++p) hv1[p] += __shfl_xor(hv1[p], mk);
        }
        if (c == 0) {
            #pragma unroll
            for (int p = 0; p < 4; ++p) hvc[wv][4 * m + p] = hv1[p];
        }
    }

    // issue stage-D FR frags + K/D rows before barrier 4 (wave 0 only uses them)
    bf16x8 dbh[4], dbl[4];
    float4 ka, kb, da, db;
    if (wv == 0) {
        #pragma unroll
        for (int ks = 0; ks < 4; ++ks) {
            const int gi = (ks * 64 + l) * 8;
            dbh[ks] = *(const bf16x8*)&FR[65536 + gi];
            dbl[ks] = *(const bf16x8*)&FR[67584 + gi];
        }
        const int dd = c & 7;
        ka = ((const float4*)Km)[dd * 2]; kb = ((const float4*)Km)[dd * 2 + 1];
        da = ((const float4*)Dm)[dd * 2]; db = ((const float4*)Dm)[dd * 2 + 1];
    }
    __syncthreads();   // barrier 4 (last): u0/hv complete

    if (wv != 0) return;   // waves 1-3 done; wave 0 finishes the block

    // ---------------- stage D (wave 0): g = u0 x W0 (3-pass hi/lo MFMA) ----------
    f32x4 accG = (f32x4){0.f, 0.f, 0.f, 0.f};
    #pragma unroll
    for (int ks = 0; ks < 4; ++ks) {
        unsigned u[8];
        *(uint4*)&u[0] = *(const uint4*)&a0pk[c * PSTR + ks * 32 + m * 8];
        *(uint4*)&u[4] = *(const uint4*)&a0pk[c * PSTR + ks * 32 + m * 8 + 4];
        bf16x8 ah, al;
        #pragma unroll
        for (int j = 0; j < 8; ++j) {
            ah[j] = (short)(u[j] >> 16);
            al[j] = (short)(u[j] & 0xFFFFu);
        }
        accG = __builtin_amdgcn_mfma_f32_16x16x32_bf16(ah, dbh[ks], accG, 0, 0, 0);
        accG = __builtin_amdgcn_mfma_f32_16x16x32_bf16(al, dbh[ks], accG, 0, 0, 0);
        accG = __builtin_amdgcn_mfma_f32_16x16x32_bf16(ah, dbl[ks], accG, 0, 0, 0);
    }

    // ---------------- tail (wave 0): force, alpha, output ------------------------
    {
        #pragma unroll
        for (int p = 0; p < 4; ++p) {
            const int s = 4 * m + p;
            const float g = accG[p];                            // g[s][c] (c<8; else 0)
            const float hvv = hvb[0][s] + hvb[1][s]
                            + hvc[0][s] + hvc[1][s] + hvc[2][s] + hvc[3][s];
            const float* xv = &xt[s * 16];
            float f = ka.x * xv[0];
            f = fmaf(ka.y, xv[1], f);  f = fmaf(ka.z, xv[2], f);  f = fmaf(ka.w, xv[3], f);
            f = fmaf(kb.x, xv[4], f);  f = fmaf(kb.y, xv[5], f);  f = fmaf(kb.z, xv[6], f);
            f = fmaf(kb.w, xv[7], f);
            f = fmaf(da.x, xv[8], f);  f = fmaf(da.y, xv[9], f);  f = fmaf(da.z, xv[10], f);
            f = fmaf(da.w, xv[11], f); f = fmaf(db.x, xv[12], f); f = fmaf(db.y, xv[13], f);
            f = fmaf(db.z, xv[14], f); f = fmaf(db.w, xv[15], f);
            f = -f;
            float pgf = g * f, pgg = g * g;                     // c>=8 lanes contribute 0
            #pragma unroll
            for (int mk = 1; mk <= 8; mk <<= 1) {
                pgf += __shfl_xor(pgf, mk);
                pgg += __shfl_xor(pgg, mk);
            }
            const float al_ = (pgf + hvv) * __builtin_amdgcn_rcpf(1.f + pgg);
            if (c < 8)
                out[(base + s) * 8 + c] = fmaf(-g, al_, f);
        }
    }
}

// ---------------- correct (slow) fallback if workspace too small -----------------
__global__ void dyn_naive(const float* __restrict__ X, const float* __restrict__ Km,
                          const float* __restrict__ Dm, const float* __restrict__ W0,
                          const float* __restrict__ b0, const float* __restrict__ W1,
                          const float* __restrict__ b1, const float* __restrict__ W2,
                          float* __restrict__ out)
{
    const long sidx = (long)blockIdx.x * 64 + threadIdx.x;
    const float* xv = X + sidx * 16;
    float h0[HDIM], dh0[HDIM], a0[HDIM], u1[HDIM];
    for (int k = 0; k < HDIM; ++k) {
        float z = b0[k], dz = 0.f;
        for (int d = 0; d < 8; ++d) { z = fmaf(W0[k*8+d], xv[d], z); dz = fmaf(W0[k*8+d], xv[8+d], dz); }
        const float h = tanhf(z), e = 1.f - h*h;
        h0[k] = h; dh0[k] = e*dz; a0[k] = -2.f*h*e*dz*dz;
    }
    float hvv = 0.f;
    for (int j = 0; j < HDIM; ++j) {
        float z = b1[j], dz = 0.f, cc = 0.f;
        for (int k = 0; k < HDIM; ++k) {
            const float w = W1[j*HDIM+k];
            z = fmaf(w, h0[k], z); dz = fmaf(w, dh0[k], dz); cc = fmaf(w, a0[k], cc);
        }
        const float h = tanhf(z), e = 1.f - h*h;
        u1[j] = W2[j]*e;
        hvv += W2[j]*(e*cc - 2.f*h*e*dz*dz);
    }
    float g[8] = {0,0,0,0,0,0,0,0};
    for (int k = 0; k < HDIM; ++k) {
        float t = 0.f;
        for (int j = 0; j < HDIM; ++j) t = fmaf(u1[j], W1[j*HDIM+k], t);
        const float u0 = (1.f - h0[k]*h0[k]) * t;
        for (int d = 0; d < 8; ++d) g[d] = fmaf(W0[k*8+d], u0, g[d]);
    }
    float fd[8], gf = 0.f, gg = 0.f;
    for (int d = 0; d < 8; ++d) {
        float a = 0.f;
        for (int k = 0; k < 8; ++k) { a = fmaf(Km[d*8+k], xv[k], a); a = fmaf(Dm[d*8+k], xv[8+k], a); }
        fd[d] = -a; gf = fmaf(g[d], fd[d], gf); gg = fmaf(g[d], g[d], gg);
    }
    const float al = (gf + hvv) / (1.f + gg);
    for (int d = 0; d < 8; ++d) out[sidx*8 + d] = fd[d] - g[d]*al;
}

extern "C" void kernel_launch(void* const* d_in, const int* in_sizes, int n_in,
                              void* d_out, int out_size, void* d_ws, size_t ws_size,
                              hipStream_t stream) {
    const float* X  = (const float*)d_in[0];
    const float* Km = (const float*)d_in[1];
    const float* Dm = (const float*)d_in[2];
    const float* W0 = (const float*)d_in[3];
    const float* b0 = (const float*)d_in[4];
    const float* W1 = (const float*)d_in[5];
    const float* b1 = (const float*)d_in[6];
    const float* W2 = (const float*)d_in[7];
    // d_in[8] = b2 (unused: cancels in grad/hessian/force)
    float* out = (float*)d_out;

    const int BATCH = in_sizes[0] / 16;        // 65536
    if (ws_size >= (size_t)(69632 * sizeof(unsigned short))) {   // 136 KiB
        unsigned short* FR = (unsigned short*)d_ws;
        prep_frags<<<72, 256, 0, stream>>>(W1, W0, FR);
        dyn_mfma<<<BATCH / S, NT, 0, stream>>>(X, Km, Dm, W0, b0, b1, W2, FR, out);
    } else {
        dyn_naive<<<BATCH / 64, 64, 0, stream>>>(X, Km, Dm, W0, b0, W1, b1, W2, out);
    }
}